// Round 4
// baseline (814.466 us; speedup 1.0000x reference)
//
#include <hip/hip_runtime.h>

typedef __bf16 bf16_t;
typedef bf16_t bf16x4 __attribute__((ext_vector_type(4)));
typedef bf16_t bf16x8 __attribute__((ext_vector_type(8)));
typedef float floatx4 __attribute__((ext_vector_type(4)));

#define EPSF 1e-5f
#define DEV static __device__ __forceinline__

// ---------------------------------------------------------------------------
// K0: swizzle weight matrices (f32 [K][128]) into B-fragment order, bf16.
// sw[((t*nK + s)*64 + l)*8 + j] = W[(s*32 + (l>>4)*8 + j)*128 + (t*16 + (l&15))]
// Layout ranges (bf16 elems): W_in@0(16384), W_ctx1@16384(32768),
// W_ctx2@49152(16384), W_m1@65536(16384), W_m2@81920(16384). Total 98304.
// ---------------------------------------------------------------------------
__global__ __launch_bounds__(256) void k_prep(
    const float* __restrict__ W_in, const float* __restrict__ W_ctx1,
    const float* __restrict__ W_ctx2, const float* __restrict__ W_m1,
    const float* __restrict__ W_m2, bf16_t* __restrict__ sw)
{
    int idx = blockIdx.x * 256 + threadIdx.x;   // grid sized to exactly 98304
    const float* W; int base, ks;
    if (idx < 16384)      { W = W_in;   base = 0;     ks = 2; }
    else if (idx < 49152) { W = W_ctx1; base = 16384; ks = 3; }
    else if (idx < 65536) { W = W_ctx2; base = 49152; ks = 2; }
    else if (idx < 81920) { W = W_m1;   base = 65536; ks = 2; }
    else                  { W = W_m2;   base = 81920; ks = 2; }
    int local = idx - base;
    int j = local & 7, l = (local >> 3) & 63, rest = local >> 9;
    int s = rest & ((1 << ks) - 1), t = rest >> ks;
    int k = s * 32 + (l >> 4) * 8 + j;
    int n = t * 16 + (l & 15);
    sw[idx] = (bf16_t)W[k * 128 + n];
}

// GroupNorm over 128 channels per row, operating on MFMA C-layout accumulators.
// acc[t][rr] holds element (row = (lane>>4)*4+rr, col = t*16 + (lane&15)).
DEV void gn_rows(floatx4* acc, int lane, const float* __restrict__ gamma,
                 const float* __restrict__ beta, bool do_relu)
{
    int m = lane & 15;
    float s1[4] = {0.f,0.f,0.f,0.f}, s2[4] = {0.f,0.f,0.f,0.f};
#pragma unroll
    for (int t = 0; t < 8; ++t)
#pragma unroll
        for (int rr = 0; rr < 4; ++rr) { float v = acc[t][rr]; s1[rr] += v; s2[rr] += v*v; }
#pragma unroll
    for (int mask = 1; mask <= 8; mask <<= 1)
#pragma unroll
        for (int rr = 0; rr < 4; ++rr) {
            s1[rr] += __shfl_xor(s1[rr], mask);
            s2[rr] += __shfl_xor(s2[rr], mask);
        }
    float mean[4], inv[4];
#pragma unroll
    for (int rr = 0; rr < 4; ++rr) {
        mean[rr] = s1[rr] * (1.f/128.f);
        float var = s2[rr] * (1.f/128.f) - mean[rr]*mean[rr];
        inv[rr] = rsqrtf(var + EPSF);
    }
#pragma unroll
    for (int t = 0; t < 8; ++t) {
        int n = t*16 + m;
        float ga = gamma[n], be = beta[n];
#pragma unroll
        for (int rr = 0; rr < 4; ++rr) {
            float v = (acc[t][rr] - mean[rr]) * inv[rr] * ga + be;
            acc[t][rr] = do_relu ? fmaxf(v, 0.f) : v;
        }
    }
}

// ---------------------------------------------------------------------------
// Binning: histogram of wi, exclusive scan -> off[Nt+1].
// ---------------------------------------------------------------------------
__global__ __launch_bounds__(256) void k_count(const int* __restrict__ wi,
                                               int* __restrict__ cnt, int E)
{
    int e = blockIdx.x * 256 + threadIdx.x;
    if (e < E) atomicAdd(&cnt[wi[e]], 1);
}

__global__ __launch_bounds__(1024) void k_scan(const int* __restrict__ cnt,
                                               int* __restrict__ off, int Nt)
{
    __shared__ int wsum[16];
    __shared__ int s_carry;
    int tid = threadIdx.x, lane = tid & 63, wid = tid >> 6;
    if (tid == 0) s_carry = 0;
    __syncthreads();
    for (int bs = 0; bs < Nt; bs += 4096) {
        int i0 = bs + tid * 4;
        int v0 = 0, v1 = 0, v2 = 0, v3 = 0;
        if (i0 + 3 < Nt) {
            int4 v = *(const int4*)(cnt + i0);
            v0 = v.x; v1 = v.y; v2 = v.z; v3 = v.w;
        } else {
            if (i0     < Nt) v0 = cnt[i0];
            if (i0 + 1 < Nt) v1 = cnt[i0+1];
            if (i0 + 2 < Nt) v2 = cnt[i0+2];
            if (i0 + 3 < Nt) v3 = cnt[i0+3];
        }
        int tot = v0 + v1 + v2 + v3;
        int x = tot;
#pragma unroll
        for (int d = 1; d < 64; d <<= 1) {
            int y = __shfl_up(x, d);
            if (lane >= d) x += y;
        }
        if (lane == 63) wsum[wid] = x;
        __syncthreads();
        if (wid == 0) {
            int wv = (lane < 16) ? wsum[lane] : 0;
#pragma unroll
            for (int d = 1; d < 16; d <<= 1) {
                int y = __shfl_up(wv, d);
                if (lane >= d) wv += y;
            }
            if (lane < 16) wsum[lane] = wv;
        }
        __syncthreads();
        int ebase = s_carry + ((wid > 0) ? wsum[wid-1] : 0) + (x - tot);
        if (i0 + 3 < Nt) {
            *(int4*)(off + i0) = make_int4(ebase, ebase+v0, ebase+v0+v1, ebase+v0+v1+v2);
        } else {
            if (i0     < Nt) off[i0]   = ebase;
            if (i0 + 1 < Nt) off[i0+1] = ebase + v0;
            if (i0 + 2 < Nt) off[i0+2] = ebase + v0 + v1;
            if (i0 + 3 < Nt) off[i0+3] = ebase + v0 + v1 + v2;
        }
        __syncthreads();
        if (tid == 0) s_carry += wsum[15];
        __syncthreads();
    }
    if (tid == 0) off[Nt] = s_carry;
}

// ---------------------------------------------------------------------------
// K2 (v4): barrier-free, direct-fragment gather, s-outer MFMA to keep only
// one A-fragment live at a time (target VGPR<=64 -> 8 waves/SIMD).
// Relpose s-slices (4..7, compute-only) run first while the cfeat float4
// prefetch is in flight; cfeat s-slices (0..3) use a 1-deep pipeline.
// LDS only for the per-wave C-layout -> row-major restage of h ([16][136]).
// One slot-claim atomic per edge; h row written as 4x16B stores.
// ---------------------------------------------------------------------------
__global__ __launch_bounds__(256, 8) void k_edge4(
    const float* __restrict__ cfeat, const float* __restrict__ cpose,
    const float* __restrict__ tpose, const int* __restrict__ hi,
    const int* __restrict__ wi, const float* __restrict__ W_rp,
    const float* __restrict__ b_rp, const float* __restrict__ g_ctx,
    const float* __restrict__ be_ctx, const bf16_t* __restrict__ swC1,
    const int* __restrict__ off, int* __restrict__ cur,
    bf16_t* __restrict__ hbuf, int E)
{
    __shared__ alignas(16) bf16_t sH[4][2176];   // per-wave [16][136] bf16
    int tid = threadIdx.x, lane = tid & 63, wave = tid >> 6;
    int tb = (blockIdx.x * 4 + wave) * 16;
    int r = lane & 15, g = lane >> 4;
    int e = min(tb + r, E - 1);
    int ci = hi[e], ti = wi[e];

    floatx4 acc[8];
#pragma unroll
    for (int t = 0; t < 8; ++t) acc[t] = (floatx4){0.f,0.f,0.f,0.f};

    // issue first cfeat prefetch (s=0), hides under relpose compute
    const float4* cf = (const float4*)(cfeat + (size_t)ci * 128);
    float4 p0 = cf[g*2], p1 = cf[g*2 + 1];

    // relpose MLP slices: K in [128,256) -> s = 4..7 (compute-only)
    float4 cp = ((const float4*)cpose)[ci];
    float4 tp = ((const float4*)tpose)[ti];
    float d0 = cp.x - tp.x, d1 = cp.y - tp.y, d2 = cp.z - tp.z, d3 = cp.w - tp.w;
#pragma unroll
    for (int sp = 0; sp < 4; ++sp) {
        int k0 = sp * 32 + g * 8;
        const float4* w0 = (const float4*)(W_rp + k0);
        const float4* w1 = (const float4*)(W_rp + 128 + k0);
        const float4* w2 = (const float4*)(W_rp + 256 + k0);
        const float4* w3 = (const float4*)(W_rp + 384 + k0);
        const float4* bb = (const float4*)(b_rp + k0);
        float o0,o1,o2,o3,o4,o5,o6,o7;
        {
            float4 a0=w0[0], a1=w1[0], a2=w2[0], a3=w3[0], ab=bb[0];
            o0 = fmaxf(d0*a0.x + d1*a1.x + d2*a2.x + d3*a3.x + ab.x, 0.f);
            o1 = fmaxf(d0*a0.y + d1*a1.y + d2*a2.y + d3*a3.y + ab.y, 0.f);
            o2 = fmaxf(d0*a0.z + d1*a1.z + d2*a2.z + d3*a3.z + ab.z, 0.f);
            o3 = fmaxf(d0*a0.w + d1*a1.w + d2*a2.w + d3*a3.w + ab.w, 0.f);
        }
        {
            float4 a0=w0[1], a1=w1[1], a2=w2[1], a3=w3[1], ab=bb[1];
            o4 = fmaxf(d0*a0.x + d1*a1.x + d2*a2.x + d3*a3.x + ab.x, 0.f);
            o5 = fmaxf(d0*a0.y + d1*a1.y + d2*a2.y + d3*a3.y + ab.y, 0.f);
            o6 = fmaxf(d0*a0.z + d1*a1.z + d2*a2.z + d3*a3.z + ab.z, 0.f);
            o7 = fmaxf(d0*a0.w + d1*a1.w + d2*a2.w + d3*a3.w + ab.w, 0.f);
        }
        bf16x8 aF = { (bf16_t)o0, (bf16_t)o1, (bf16_t)o2, (bf16_t)o3,
                      (bf16_t)o4, (bf16_t)o5, (bf16_t)o6, (bf16_t)o7 };
        int s = 4 + sp;
#pragma unroll
        for (int t = 0; t < 8; ++t) {
            bf16x8 bF = *(const bf16x8*)&swC1[(size_t)((t*8 + s)*64 + lane)*8];
            acc[t] = __builtin_amdgcn_mfma_f32_16x16x32_bf16(aF, bF, acc[t], 0, 0, 0);
        }
    }
    // cfeat slices: K in [0,128) -> s = 0..3, 1-deep prefetch pipeline
#pragma unroll
    for (int s = 0; s < 4; ++s) {
        float4 v0 = p0, v1 = p1;
        if (s < 3) { p0 = cf[(s+1)*8 + g*2]; p1 = cf[(s+1)*8 + g*2 + 1]; }
        bf16x8 aF = { (bf16_t)v0.x, (bf16_t)v0.y, (bf16_t)v0.z, (bf16_t)v0.w,
                      (bf16_t)v1.x, (bf16_t)v1.y, (bf16_t)v1.z, (bf16_t)v1.w };
#pragma unroll
        for (int t = 0; t < 8; ++t) {
            bf16x8 bF = *(const bf16x8*)&swC1[(size_t)((t*8 + s)*64 + lane)*8];
            acc[t] = __builtin_amdgcn_mfma_f32_16x16x32_bf16(aF, bF, acc[t], 0, 0, 0);
        }
    }
    gn_rows(acc, lane, g_ctx, be_ctx, true);

    // restage h into per-wave LDS: row = g*4+rr, col = t*16 + r  (conflict-free)
#pragma unroll
    for (int t = 0; t < 8; ++t)
#pragma unroll
        for (int rr = 0; rr < 4; ++rr)
            sH[wave][(g*4 + rr)*136 + t*16 + r] = (bf16_t)acc[t][rr];

    // write-out: 4 lanes per row; one slot-claim atomic per edge
    int r2 = lane >> 2, c2 = lane & 3;
    int e2 = tb + r2;
    bool ev2 = e2 < E;
    int dst = 0;
    if (ev2 && c2 == 0) {
        int t2 = wi[e2];
        dst = off[t2] + atomicAdd(&cur[t2], 1);
    }
    dst = __shfl(dst, lane & ~3);
    if (ev2) {
        bf16_t* hp = hbuf + (size_t)dst * 128 + c2 * 32;
#pragma unroll
        for (int i = 0; i < 4; ++i)
            *(bf16x8*)(hp + i*8) = *(const bf16x8*)&sH[wave][r2*136 + c2*32 + i*8];
    }
}

// ---------------------------------------------------------------------------
// K3 (v3): barrier-free, per-wave independent. Per 16 target rows:
//   tf = tfeat@W_in + (sum of binned h rows)@W_ctx2   (fused MFMA chain)
//   out = relu(GN(relu(GN(relu(GN(tf)) @ W_m1)) @ W_m2) + tfeat)
// Direct-fragment tfeat loads; bin gather-sum lands directly in the lane's
// own A-frag chunk (rows of the bin are contiguous). aH spilled to per-wave
// LDS to stay under the 64-VGPR cliff. s-outer MFMA; GN restages via the
// conflict-free per-wave [16][136] buffer. No __syncthreads anywhere.
// ---------------------------------------------------------------------------
__global__ __launch_bounds__(256, 8) void k_out3(
    const float* __restrict__ tfeat, const bf16_t* __restrict__ hbuf,
    const int* __restrict__ off,
    const float* __restrict__ g_n, const float* __restrict__ be_n,
    const float* __restrict__ g_m1, const float* __restrict__ be_m1,
    const float* __restrict__ g_m2, const float* __restrict__ be_m2,
    const bf16_t* __restrict__ swIn, const bf16_t* __restrict__ swC2,
    const bf16_t* __restrict__ swM1, const bf16_t* __restrict__ swM2,
    float* __restrict__ out, int Nt)
{
    __shared__ alignas(16) bf16_t sB[4][2176];   // per-wave [16][136] bf16
    int tid = threadIdx.x, lane = tid & 63, wave = tid >> 6;
    int tb = (blockIdx.x*4 + wave)*16;
    int r = lane & 15, g = lane >> 4;
    int grow = tb + r;
    bool rv = grow < Nt;
    int rclamp = rv ? grow : (Nt - 1);

    // ---- bin gather-sum straight into this lane's A-frag cols {s*32+g*8..+8}
    float sums[32];
#pragma unroll
    for (int i = 0; i < 32; ++i) sums[i] = 0.f;
    int jb = rv ? off[grow] : 0, je = rv ? off[grow+1] : 0;
    for (int jr = jb; jr < je; ++jr) {
        const bf16_t* hp = hbuf + (size_t)jr*128 + g*8;
#pragma unroll
        for (int s = 0; s < 4; ++s) {
            bf16x8 hv = *(const bf16x8*)(hp + s*32);
#pragma unroll
            for (int q = 0; q < 8; ++q) sums[s*8+q] += (float)hv[q];
        }
    }
    // spill Hsum A-frags to per-wave LDS (frees 32 f32 regs; lane-local data)
#pragma unroll
    for (int s = 0; s < 4; ++s) {
        bf16x8 ah = { (bf16_t)sums[s*8+0], (bf16_t)sums[s*8+1],
                      (bf16_t)sums[s*8+2], (bf16_t)sums[s*8+3],
                      (bf16_t)sums[s*8+4], (bf16_t)sums[s*8+5],
                      (bf16_t)sums[s*8+6], (bf16_t)sums[s*8+7] };
        *(bf16x8*)&sB[wave][r*136 + s*32 + g*8] = ah;
    }

    // ---- gemm1: acc = tfeat@W_in + Hsum@W_ctx2  (s-outer, 1-deep prefetch)
    floatx4 acc[8];
#pragma unroll
    for (int t = 0; t < 8; ++t) acc[t] = (floatx4){0.f,0.f,0.f,0.f};
    const float4* cf = (const float4*)(tfeat + (size_t)rclamp * 128);
    float4 p0 = cf[g*2], p1 = cf[g*2 + 1];
#pragma unroll
    for (int s = 0; s < 4; ++s) {
        bf16x8 aH = *(const bf16x8*)&sB[wave][r*136 + s*32 + g*8];
#pragma unroll
        for (int t = 0; t < 8; ++t) {
            bf16x8 bF = *(const bf16x8*)&swC2[((t*4+s)*64 + lane)*8];
            acc[t] = __builtin_amdgcn_mfma_f32_16x16x32_bf16(aH, bF, acc[t], 0, 0, 0);
        }
        float4 v0 = p0, v1 = p1;
        if (s < 3) { p0 = cf[(s+1)*8 + g*2]; p1 = cf[(s+1)*8 + g*2 + 1]; }
        bf16x8 aF = { (bf16_t)v0.x, (bf16_t)v0.y, (bf16_t)v0.z, (bf16_t)v0.w,
                      (bf16_t)v1.x, (bf16_t)v1.y, (bf16_t)v1.z, (bf16_t)v1.w };
#pragma unroll
        for (int t = 0; t < 8; ++t) {
            bf16x8 bF = *(const bf16x8*)&swIn[((t*4+s)*64 + lane)*8];
            acc[t] = __builtin_amdgcn_mfma_f32_16x16x32_bf16(aF, bF, acc[t], 0, 0, 0);
        }
    }
    gn_rows(acc, lane, g_n, be_n, true);

    // ---- restage -> gemm2 (W_m1)
#pragma unroll
    for (int t = 0; t < 8; ++t)
#pragma unroll
        for (int rr = 0; rr < 4; ++rr)
            sB[wave][(g*4 + rr)*136 + t*16 + r] = (bf16_t)acc[t][rr];
#pragma unroll
    for (int t = 0; t < 8; ++t) acc[t] = (floatx4){0.f,0.f,0.f,0.f};
#pragma unroll
    for (int s = 0; s < 4; ++s) {
        bf16x8 aF = *(const bf16x8*)&sB[wave][r*136 + s*32 + g*8];
#pragma unroll
        for (int t = 0; t < 8; ++t) {
            bf16x8 bF = *(const bf16x8*)&swM1[((t*4+s)*64 + lane)*8];
            acc[t] = __builtin_amdgcn_mfma_f32_16x16x32_bf16(aF, bF, acc[t], 0, 0, 0);
        }
    }
    gn_rows(acc, lane, g_m1, be_m1, true);

    // ---- restage -> gemm3 (W_m2)
#pragma unroll
    for (int t = 0; t < 8; ++t)
#pragma unroll
        for (int rr = 0; rr < 4; ++rr)
            sB[wave][(g*4 + rr)*136 + t*16 + r] = (bf16_t)acc[t][rr];
#pragma unroll
    for (int t = 0; t < 8; ++t) acc[t] = (floatx4){0.f,0.f,0.f,0.f};
#pragma unroll
    for (int s = 0; s < 4; ++s) {
        bf16x8 aF = *(const bf16x8*)&sB[wave][r*136 + s*32 + g*8];
#pragma unroll
        for (int t = 0; t < 8; ++t) {
            bf16x8 bF = *(const bf16x8*)&swM2[((t*4+s)*64 + lane)*8];
            acc[t] = __builtin_amdgcn_mfma_f32_16x16x32_bf16(aF, bF, acc[t], 0, 0, 0);
        }
    }
    gn_rows(acc, lane, g_m2, be_m2, false);

    // ---- epilogue: +identity, relu, direct C-layout stores (64B segments)
#pragma unroll
    for (int t = 0; t < 8; ++t) {
        int n = t*16 + r;
#pragma unroll
        for (int rr = 0; rr < 4; ++rr) {
            int row = tb + g*4 + rr;
            if (row < Nt) {
                float v = acc[t][rr] + tfeat[(size_t)row*128 + n];
                out[(size_t)row*128 + n] = fmaxf(v, 0.f);
            }
        }
    }
}

// ===========================================================================
// FALLBACK PATH (previous kernels, used only if workspace is too small for
// the binned h buffer).
// ===========================================================================
__global__ __launch_bounds__(256) void k_gemm_in(
    const float* __restrict__ tfeat, const bf16_t* __restrict__ swW,
    float* __restrict__ tf, int Nt)
{
    __shared__ alignas(16) bf16_t sA[4][2048];
    int tid = threadIdx.x, lane = tid & 63, wave = tid >> 6;

    int tb = (blockIdx.x * 4 + wave) * 16;
    int r = lane >> 2, cb = (lane & 3) * 32;
    int grow = tb + r;
    bool rv = grow < Nt;
    const float4* src = (const float4*)(tfeat + (size_t)(rv ? grow : 0) * 128 + cb);
#pragma unroll
    for (int i = 0; i < 8; ++i) {
        float4 v = rv ? src[i] : make_float4(0.f,0.f,0.f,0.f);
        int k = cb + 4*i;
        int s = k >> 5, q = (k >> 3) & 3, j = k & 7;
        bf16x4 pk = { (bf16_t)v.x, (bf16_t)v.y, (bf16_t)v.z, (bf16_t)v.w };
        *(bf16x4*)&sA[wave][(s*64 + q*16 + r)*8 + j] = pk;
    }
    __syncthreads();
    int m = lane & 15, g = lane >> 4;
    bf16x8 aF[4];
#pragma unroll
    for (int s = 0; s < 4; ++s) aF[s] = *(const bf16x8*)&sA[wave][(s*64 + lane)*8];
#pragma unroll
    for (int t = 0; t < 8; ++t) {
        floatx4 a = {0.f,0.f,0.f,0.f};
#pragma unroll
        for (int s = 0; s < 4; ++s) {
            bf16x8 bF = *(const bf16x8*)&swW[((t*4+s)*64 + lane)*8];
            a = __builtin_amdgcn_mfma_f32_16x16x32_bf16(aF[s], bF, a, 0, 0, 0);
        }
#pragma unroll
        for (int rr = 0; rr < 4; ++rr) {
            int row = tb + g*4 + rr;
            if (row < Nt) tf[(size_t)row*128 + t*16 + m] = a[rr];
        }
    }
}

__global__ __launch_bounds__(256) void k_edge_old(
    const float* __restrict__ cfeat, const float* __restrict__ cpose,
    const float* __restrict__ tpose, const int* __restrict__ hi,
    const int* __restrict__ wi, const float* __restrict__ W_rp,
    const float* __restrict__ b_rp, const float* __restrict__ g_ctx,
    const float* __restrict__ be_ctx, const bf16_t* __restrict__ swC1,
    const bf16_t* __restrict__ swC2, float* __restrict__ tf, int E)
{
    __shared__ alignas(16) bf16_t sA[4][4096];
    int tid = threadIdx.x, lane = tid & 63, wave = tid >> 6;

    int tb = (blockIdx.x * 4 + wave) * 16;
    int r = lane >> 2, cb = (lane & 3) * 32;
    int e = min(tb + r, E - 1);
    int ci = hi[e], ti = wi[e];
    const float4* src = (const float4*)(cfeat + (size_t)ci * 128 + cb);
#pragma unroll
    for (int i = 0; i < 8; ++i) {
        float4 v = src[i];
        int k = cb + 4*i;
        int s = k >> 5, q = (k >> 3) & 3, j = k & 7;
        bf16x4 pk = { (bf16_t)v.x, (bf16_t)v.y, (bf16_t)v.z, (bf16_t)v.w };
        *(bf16x4*)&sA[wave][(s*64 + q*16 + r)*8 + j] = pk;
    }
    float4 cp = ((const float4*)cpose)[ci];
    float4 tp = ((const float4*)tpose)[ti];
    float d0 = cp.x - tp.x, d1 = cp.y - tp.y, d2 = cp.z - tp.z, d3 = cp.w - tp.w;
#pragma unroll
    for (int i = 0; i < 8; ++i) {
        int cc = cb + 4*i;
        float4 w0 = *(const float4*)(W_rp + cc);
        float4 w1 = *(const float4*)(W_rp + 128 + cc);
        float4 w2 = *(const float4*)(W_rp + 256 + cc);
        float4 w3 = *(const float4*)(W_rp + 384 + cc);
        float4 bb = *(const float4*)(b_rp + cc);
        float o0 = fmaxf(d0*w0.x + d1*w1.x + d2*w2.x + d3*w3.x + bb.x, 0.f);
        float o1 = fmaxf(d0*w0.y + d1*w1.y + d2*w2.y + d3*w3.y + bb.y, 0.f);
        float o2 = fmaxf(d0*w0.z + d1*w1.z + d2*w2.z + d3*w3.z + bb.z, 0.f);
        float o3 = fmaxf(d0*w0.w + d1*w1.w + d2*w2.w + d3*w3.w + bb.w, 0.f);
        int k = 128 + cc;
        int s = k >> 5, q = (k >> 3) & 3, j = k & 7;
        bf16x4 pk = { (bf16_t)o0, (bf16_t)o1, (bf16_t)o2, (bf16_t)o3 };
        *(bf16x4*)&sA[wave][(s*64 + q*16 + r)*8 + j] = pk;
    }
    __syncthreads();

    int m = lane & 15, g = lane >> 4;
    bf16x8 aF[8];
#pragma unroll
    for (int s = 0; s < 8; ++s) aF[s] = *(const bf16x8*)&sA[wave][(s*64 + lane)*8];
    floatx4 acc[8];
#pragma unroll
    for (int t = 0; t < 8; ++t) {
        floatx4 a = {0.f,0.f,0.f,0.f};
#pragma unroll
        for (int s = 0; s < 8; ++s) {
            bf16x8 bF = *(const bf16x8*)&swC1[(size_t)((t*8+s)*64 + lane)*8];
            a = __builtin_amdgcn_mfma_f32_16x16x32_bf16(aF[s], bF, a, 0, 0, 0);
        }
        acc[t] = a;
    }
    gn_rows(acc, lane, g_ctx, be_ctx, true);
    __syncthreads();
#pragma unroll
    for (int t = 0; t < 8; ++t) {
        int n = t*16 + m;
        int s = n >> 5, q = (n >> 3) & 3, j = n & 7;
#pragma unroll
        for (int rr = 0; rr < 4; ++rr)
            sA[wave][(s*64 + q*16 + (g*4+rr))*8 + j] = (bf16_t)acc[t][rr];
    }
    __syncthreads();
    bf16x8 aF2[4];
#pragma unroll
    for (int s = 0; s < 4; ++s) aF2[s] = *(const bf16x8*)&sA[wave][(s*64 + lane)*8];
    int dstrow[4]; bool vald[4];
#pragma unroll
    for (int rr = 0; rr < 4; ++rr) {
        int ee = tb + g*4 + rr;
        vald[rr] = ee < E;
        dstrow[rr] = vald[rr] ? wi[ee] : 0;
    }
#pragma unroll
    for (int t = 0; t < 8; ++t) {
        floatx4 a = {0.f,0.f,0.f,0.f};
#pragma unroll
        for (int s = 0; s < 4; ++s) {
            bf16x8 bF = *(const bf16x8*)&swC2[((t*4+s)*64 + lane)*8];
            a = __builtin_amdgcn_mfma_f32_16x16x32_bf16(aF2[s], bF, a, 0, 0, 0);
        }
#pragma unroll
        for (int rr = 0; rr < 4; ++rr) {
            if (vald[rr])
                atomicAdd(&tf[(size_t)dstrow[rr]*128 + t*16 + m], a[rr]);
        }
    }
}

__global__ __launch_bounds__(256) void k_out_old(
    const float* __restrict__ tf, const float* __restrict__ identity,
    const float* __restrict__ g_n, const float* __restrict__ be_n,
    const float* __restrict__ g_m1, const float* __restrict__ be_m1,
    const float* __restrict__ g_m2, const float* __restrict__ be_m2,
    const bf16_t* __restrict__ swM1, const bf16_t* __restrict__ swM2,
    float* __restrict__ out, int Nt)
{
    __shared__ alignas(16) bf16_t sA[4][2048];
    int tid = threadIdx.x, lane = tid & 63, wave = tid >> 6;

    int tb = (blockIdx.x*4 + wave)*16;
    int r = lane >> 2, cb = (lane & 3)*32;
    int grow = tb + r;
    bool rv = grow < Nt;
    const float4* src = (const float4*)(tf + (size_t)(rv ? grow : 0)*128 + cb);
    float vals[32];
    float ls = 0.f, lq = 0.f;
#pragma unroll
    for (int i = 0; i < 8; ++i) {
        float4 v = rv ? src[i] : make_float4(0.f,0.f,0.f,0.f);
        vals[4*i+0]=v.x; vals[4*i+1]=v.y; vals[4*i+2]=v.z; vals[4*i+3]=v.w;
        ls += v.x+v.y+v.z+v.w;
        lq += v.x*v.x+v.y*v.y+v.z*v.z+v.w*v.w;
    }
    ls += __shfl_xor(ls,1); lq += __shfl_xor(lq,1);
    ls += __shfl_xor(ls,2); lq += __shfl_xor(lq,2);
    float mean = ls*(1.f/128.f);
    float inv = rsqrtf(lq*(1.f/128.f) - mean*mean + EPSF);
#pragma unroll
    for (int i = 0; i < 8; ++i) {
        int cc = cb + 4*i;
        float4 ga = *(const float4*)(g_n + cc);
        float4 be = *(const float4*)(be_n + cc);
        float o0 = fmaxf((vals[4*i+0]-mean)*inv*ga.x + be.x, 0.f);
        float o1 = fmaxf((vals[4*i+1]-mean)*inv*ga.y + be.y, 0.f);
        float o2 = fmaxf((vals[4*i+2]-mean)*inv*ga.z + be.z, 0.f);
        float o3 = fmaxf((vals[4*i+3]-mean)*inv*ga.w + be.w, 0.f);
        int s = cc >> 5, q = (cc >> 3) & 3, j = cc & 7;
        bf16x4 pk = { (bf16_t)o0, (bf16_t)o1, (bf16_t)o2, (bf16_t)o3 };
        *(bf16x4*)&sA[wave][(s*64 + q*16 + r)*8 + j] = pk;
    }
    __syncthreads();
    int m = lane & 15, g = lane >> 4;
    bf16x8 aF[4];
#pragma unroll
    for (int s = 0; s < 4; ++s) aF[s] = *(const bf16x8*)&sA[wave][(s*64 + lane)*8];
    floatx4 acc[8];
#pragma unroll
    for (int t = 0; t < 8; ++t) {
        floatx4 a = {0.f,0.f,0.f,0.f};
#pragma unroll
        for (int s = 0; s < 4; ++s) {
            bf16x8 bF = *(const bf16x8*)&swM1[((t*4+s)*64 + lane)*8];
            a = __builtin_amdgcn_mfma_f32_16x16x32_bf16(aF[s], bF, a, 0, 0, 0);
        }
        acc[t] = a;
    }
    gn_rows(acc, lane, g_m1, be_m1, true);
    __syncthreads();
#pragma unroll
    for (int t = 0; t < 8; ++t) {
        int n = t*16 + m;
        int s = n >> 5, q = (n >> 3) & 3, j = n & 7;
#pragma unroll
        for (int rr = 0; rr < 4; ++rr)
            sA[wave][(s*64 + q*16 + (g*4+rr))*8 + j] = (bf16_t)acc[t][rr];
    }
    __syncthreads();
#pragma unroll
    for (int s = 0; s < 4; ++s) aF[s] = *(const bf16x8*)&sA[wave][(s*64 + lane)*8];
#pragma unroll
    for (int t = 0; t < 8; ++t) {
        floatx4 a = {0.f,0.f,0.f,0.f};
#pragma unroll
        for (int s = 0; s < 4; ++s) {
            bf16x8 bF = *(const bf16x8*)&swM2[((t*4+s)*64 + lane)*8];
            a = __builtin_amdgcn_mfma_f32_16x16x32_bf16(aF[s], bF, a, 0, 0, 0);
        }
        acc[t] = a;
    }
    gn_rows(acc, lane, g_m2, be_m2, false);
#pragma unroll
    for (int t = 0; t < 8; ++t) {
        int n = t*16 + m;
#pragma unroll
        for (int rr = 0; rr < 4; ++rr) {
            int row = tb + g*4 + rr;
            if (row < Nt) {
                float v = acc[t][rr] + identity[(size_t)row*128 + n];
                out[(size_t)row*128 + n] = fmaxf(v, 0.f);
            }
        }
    }
}

// ---------------------------------------------------------------------------
extern "C" void kernel_launch(void* const* d_in, const int* in_sizes, int n_in,
                              void* d_out, int out_size, void* d_ws, size_t ws_size,
                              hipStream_t stream)
{
    const float* cfeat  = (const float*)d_in[0];
    const float* tfeat  = (const float*)d_in[1];
    const float* cpose  = (const float*)d_in[2];
    const float* tpose  = (const float*)d_in[3];
    const int*   hi     = (const int*)d_in[4];
    const int*   wi     = (const int*)d_in[5];
    const float* W_in   = (const float*)d_in[6];
    const float* W_rp   = (const float*)d_in[7];
    const float* b_rp   = (const float*)d_in[8];
    const float* W_ctx1 = (const float*)d_in[9];
    const float* g_ctx  = (const float*)d_in[10];
    const float* be_ctx = (const float*)d_in[11];
    const float* W_ctx2 = (const float*)d_in[12];
    const float* g_n    = (const float*)d_in[13];
    const float* be_n   = (const float*)d_in[14];
    const float* W_m1   = (const float*)d_in[15];
    const float* g_m1   = (const float*)d_in[16];
    const float* be_m1  = (const float*)d_in[17];
    const float* W_m2   = (const float*)d_in[18];
    const float* g_m2   = (const float*)d_in[19];
    const float* be_m2  = (const float*)d_in[20];

    int Nt = in_sizes[1] / 128;
    int E  = in_sizes[4];
    float* outp = (float*)d_out;

    // new-path workspace layout
    char* base = (char*)d_ws;
    size_t o = 98304 * sizeof(bf16_t);                 // sw @ 0
    o = (o + 255) & ~(size_t)255;
    size_t o_cnt = o; o += (size_t)Nt * 4;
    o = (o + 255) & ~(size_t)255;
    size_t o_off = o; o += ((size_t)Nt + 1) * 4;
    o = (o + 255) & ~(size_t)255;
    size_t o_cur = o; o += (size_t)Nt * 4;
    o = (o + 255) & ~(size_t)255;
    size_t o_h = o; o += (size_t)E * 128 * sizeof(bf16_t);

    if (ws_size >= o) {
        bf16_t* sw   = (bf16_t*)base;
        int*    cnt  = (int*)(base + o_cnt);
        int*    off  = (int*)(base + o_off);
        int*    cur  = (int*)(base + o_cur);
        bf16_t* hbuf = (bf16_t*)(base + o_h);
        bf16_t* swIn = sw;
        bf16_t* swC1 = sw + 16384;
        bf16_t* swC2 = sw + 49152;
        bf16_t* swM1 = sw + 65536;
        bf16_t* swM2 = sw + 81920;

        hipMemsetAsync(cnt, 0, (size_t)Nt * 4, stream);
        hipMemsetAsync(cur, 0, (size_t)Nt * 4, stream);
        k_prep<<<384, 256, 0, stream>>>(W_in, W_ctx1, W_ctx2, W_m1, W_m2, sw);
        k_count<<<(E + 255) / 256, 256, 0, stream>>>(wi, cnt, E);
        k_scan<<<1, 1024, 0, stream>>>(cnt, off, Nt);
        k_edge4<<<(E + 63) / 64, 256, 0, stream>>>(cfeat, cpose, tpose, hi, wi,
                                                   W_rp, b_rp, g_ctx, be_ctx,
                                                   swC1, off, cur, hbuf, E);
        k_out3<<<(Nt + 63) / 64, 256, 0, stream>>>(tfeat, hbuf, off,
                                                   g_n, be_n, g_m1, be_m1,
                                                   g_m2, be_m2,
                                                   swIn, swC2, swM1, swM2,
                                                   outp, Nt);
    } else {
        // fallback: previous atomic-scatter path
        float*  tf = (float*)d_ws;                                   // [Nt,128] f32
        bf16_t* sw = (bf16_t*)((char*)d_ws + (size_t)Nt * 128 * sizeof(float));
        bf16_t* swIn = sw;
        bf16_t* swC1 = sw + 16384;
        bf16_t* swC2 = sw + 49152;
        bf16_t* swM1 = sw + 65536;
        bf16_t* swM2 = sw + 81920;

        k_prep<<<384, 256, 0, stream>>>(W_in, W_ctx1, W_ctx2, W_m1, W_m2, sw);
        k_gemm_in<<<(Nt + 63) / 64, 256, 0, stream>>>(tfeat, swIn, tf, Nt);
        k_edge_old<<<(E + 63) / 64, 256, 0, stream>>>(cfeat, cpose, tpose, hi, wi,
                                                      W_rp, b_rp, g_ctx, be_ctx,
                                                      swC1, swC2, tf, E);
        k_out_old<<<(Nt + 63) / 64, 256, 0, stream>>>(tf, tfeat, g_n, be_n,
                                                      g_m1, be_m1, g_m2, be_m2,
                                                      swM1, swM2, outp, Nt);
    }
}

// Round 5
// 484.986 us; speedup vs baseline: 1.6794x; 1.6794x over previous
//
#include <hip/hip_runtime.h>

typedef __bf16 bf16_t;
typedef bf16_t bf16x4 __attribute__((ext_vector_type(4)));
typedef bf16_t bf16x8 __attribute__((ext_vector_type(8)));
typedef float floatx4 __attribute__((ext_vector_type(4)));

#define EPSF 1e-5f
#define DEV static __device__ __forceinline__

// ---------------------------------------------------------------------------
// K0: swizzle weight matrices (f32 [K][128]) into B-fragment order, bf16.
// sw[((t*nK + s)*64 + l)*8 + j] = W[(s*32 + (l>>4)*8 + j)*128 + (t*16 + (l&15))]
// Layout ranges (bf16 elems): W_in@0(16384), W_ctx1@16384(32768),
// W_ctx2@49152(16384), W_m1@65536(16384), W_m2@81920(16384). Total 98304.
// ---------------------------------------------------------------------------
__global__ __launch_bounds__(256) void k_prep(
    const float* __restrict__ W_in, const float* __restrict__ W_ctx1,
    const float* __restrict__ W_ctx2, const float* __restrict__ W_m1,
    const float* __restrict__ W_m2, bf16_t* __restrict__ sw)
{
    int idx = blockIdx.x * 256 + threadIdx.x;   // grid sized to exactly 98304
    const float* W; int base, ks;
    if (idx < 16384)      { W = W_in;   base = 0;     ks = 2; }
    else if (idx < 49152) { W = W_ctx1; base = 16384; ks = 3; }
    else if (idx < 65536) { W = W_ctx2; base = 49152; ks = 2; }
    else if (idx < 81920) { W = W_m1;   base = 65536; ks = 2; }
    else                  { W = W_m2;   base = 81920; ks = 2; }
    int local = idx - base;
    int j = local & 7, l = (local >> 3) & 63, rest = local >> 9;
    int s = rest & ((1 << ks) - 1), t = rest >> ks;
    int k = s * 32 + (l >> 4) * 8 + j;
    int n = t * 16 + (l & 15);
    sw[idx] = (bf16_t)W[k * 128 + n];
}

// GroupNorm over 128 channels per row, operating on MFMA C-layout accumulators.
// acc[t][rr] holds element (row = (lane>>4)*4+rr, col = t*16 + (lane&15)).
DEV void gn_rows(floatx4* acc, int lane, const float* __restrict__ gamma,
                 const float* __restrict__ beta, bool do_relu)
{
    int m = lane & 15;
    float s1[4] = {0.f,0.f,0.f,0.f}, s2[4] = {0.f,0.f,0.f,0.f};
#pragma unroll
    for (int t = 0; t < 8; ++t)
#pragma unroll
        for (int rr = 0; rr < 4; ++rr) { float v = acc[t][rr]; s1[rr] += v; s2[rr] += v*v; }
#pragma unroll
    for (int mask = 1; mask <= 8; mask <<= 1)
#pragma unroll
        for (int rr = 0; rr < 4; ++rr) {
            s1[rr] += __shfl_xor(s1[rr], mask);
            s2[rr] += __shfl_xor(s2[rr], mask);
        }
    float mean[4], inv[4];
#pragma unroll
    for (int rr = 0; rr < 4; ++rr) {
        mean[rr] = s1[rr] * (1.f/128.f);
        float var = s2[rr] * (1.f/128.f) - mean[rr]*mean[rr];
        inv[rr] = rsqrtf(var + EPSF);
    }
#pragma unroll
    for (int t = 0; t < 8; ++t) {
        int n = t*16 + m;
        float ga = gamma[n], be = beta[n];
#pragma unroll
        for (int rr = 0; rr < 4; ++rr) {
            float v = (acc[t][rr] - mean[rr]) * inv[rr] * ga + be;
            acc[t][rr] = do_relu ? fmaxf(v, 0.f) : v;
        }
    }
}

// ---------------------------------------------------------------------------
// Binning: histogram of wi, exclusive scan -> off[Nt+1].
// ---------------------------------------------------------------------------
__global__ __launch_bounds__(256) void k_count(const int* __restrict__ wi,
                                               int* __restrict__ cnt, int E)
{
    int e = blockIdx.x * 256 + threadIdx.x;
    if (e < E) atomicAdd(&cnt[wi[e]], 1);
}

__global__ __launch_bounds__(1024) void k_scan(const int* __restrict__ cnt,
                                               int* __restrict__ off, int Nt)
{
    __shared__ int wsum[16];
    __shared__ int s_carry;
    int tid = threadIdx.x, lane = tid & 63, wid = tid >> 6;
    if (tid == 0) s_carry = 0;
    __syncthreads();
    for (int bs = 0; bs < Nt; bs += 4096) {
        int i0 = bs + tid * 4;
        int v0 = 0, v1 = 0, v2 = 0, v3 = 0;
        if (i0 + 3 < Nt) {
            int4 v = *(const int4*)(cnt + i0);
            v0 = v.x; v1 = v.y; v2 = v.z; v3 = v.w;
        } else {
            if (i0     < Nt) v0 = cnt[i0];
            if (i0 + 1 < Nt) v1 = cnt[i0+1];
            if (i0 + 2 < Nt) v2 = cnt[i0+2];
            if (i0 + 3 < Nt) v3 = cnt[i0+3];
        }
        int tot = v0 + v1 + v2 + v3;
        int x = tot;
#pragma unroll
        for (int d = 1; d < 64; d <<= 1) {
            int y = __shfl_up(x, d);
            if (lane >= d) x += y;
        }
        if (lane == 63) wsum[wid] = x;
        __syncthreads();
        if (wid == 0) {
            int wv = (lane < 16) ? wsum[lane] : 0;
#pragma unroll
            for (int d = 1; d < 16; d <<= 1) {
                int y = __shfl_up(wv, d);
                if (lane >= d) wv += y;
            }
            if (lane < 16) wsum[lane] = wv;
        }
        __syncthreads();
        int ebase = s_carry + ((wid > 0) ? wsum[wid-1] : 0) + (x - tot);
        if (i0 + 3 < Nt) {
            *(int4*)(off + i0) = make_int4(ebase, ebase+v0, ebase+v0+v1, ebase+v0+v1+v2);
        } else {
            if (i0     < Nt) off[i0]   = ebase;
            if (i0 + 1 < Nt) off[i0+1] = ebase + v0;
            if (i0 + 2 < Nt) off[i0+2] = ebase + v0 + v1;
            if (i0 + 3 < Nt) off[i0+3] = ebase + v0 + v1 + v2;
        }
        __syncthreads();
        if (tid == 0) s_carry += wsum[15];
        __syncthreads();
    }
    if (tid == 0) off[Nt] = s_carry;
}

// ---------------------------------------------------------------------------
// K2 (v5): round-4 verified structure, natural register budget (no forced
// occupancy -> no spill), and ALL 8 cfeat gathers issued up front so the
// relpose-MFMA section covers one latency exposure instead of four.
// Barrier-free; LDS only for the per-wave [16][136] h restage.
// ---------------------------------------------------------------------------
__global__ __launch_bounds__(256) void k_edge5(
    const float* __restrict__ cfeat, const float* __restrict__ cpose,
    const float* __restrict__ tpose, const int* __restrict__ hi,
    const int* __restrict__ wi, const float* __restrict__ W_rp,
    const float* __restrict__ b_rp, const float* __restrict__ g_ctx,
    const float* __restrict__ be_ctx, const bf16_t* __restrict__ swC1,
    const int* __restrict__ off, int* __restrict__ cur,
    bf16_t* __restrict__ hbuf, int E)
{
    __shared__ alignas(16) bf16_t sH[4][2176];   // per-wave [16][136] bf16
    int tid = threadIdx.x, lane = tid & 63, wave = tid >> 6;
    int tb = (blockIdx.x * 4 + wave) * 16;
    int r = lane & 15, g = lane >> 4;
    int e = min(tb + r, E - 1);
    int ci = hi[e], ti = wi[e];

    floatx4 acc[8];
#pragma unroll
    for (int t = 0; t < 8; ++t) acc[t] = (floatx4){0.f,0.f,0.f,0.f};

    // issue ALL cfeat gathers up front (8 x global_load_dwordx4 in flight)
    const float4* cf = (const float4*)(cfeat + (size_t)ci * 128);
    float4 p[8];
#pragma unroll
    for (int s = 0; s < 4; ++s) {
        p[2*s]   = cf[s*8 + g*2];
        p[2*s+1] = cf[s*8 + g*2 + 1];
    }

    // relpose MLP slices: K in [128,256) -> s = 4..7 (compute-only, covers loads)
    float4 cp = ((const float4*)cpose)[ci];
    float4 tp = ((const float4*)tpose)[ti];
    float d0 = cp.x - tp.x, d1 = cp.y - tp.y, d2 = cp.z - tp.z, d3 = cp.w - tp.w;
#pragma unroll
    for (int sp = 0; sp < 4; ++sp) {
        int k0 = sp * 32 + g * 8;
        const float4* w0 = (const float4*)(W_rp + k0);
        const float4* w1 = (const float4*)(W_rp + 128 + k0);
        const float4* w2 = (const float4*)(W_rp + 256 + k0);
        const float4* w3 = (const float4*)(W_rp + 384 + k0);
        const float4* bb = (const float4*)(b_rp + k0);
        float o0,o1,o2,o3,o4,o5,o6,o7;
        {
            float4 a0=w0[0], a1=w1[0], a2=w2[0], a3=w3[0], ab=bb[0];
            o0 = fmaxf(d0*a0.x + d1*a1.x + d2*a2.x + d3*a3.x + ab.x, 0.f);
            o1 = fmaxf(d0*a0.y + d1*a1.y + d2*a2.y + d3*a3.y + ab.y, 0.f);
            o2 = fmaxf(d0*a0.z + d1*a1.z + d2*a2.z + d3*a3.z + ab.z, 0.f);
            o3 = fmaxf(d0*a0.w + d1*a1.w + d2*a2.w + d3*a3.w + ab.w, 0.f);
        }
        {
            float4 a0=w0[1], a1=w1[1], a2=w2[1], a3=w3[1], ab=bb[1];
            o4 = fmaxf(d0*a0.x + d1*a1.x + d2*a2.x + d3*a3.x + ab.x, 0.f);
            o5 = fmaxf(d0*a0.y + d1*a1.y + d2*a2.y + d3*a3.y + ab.y, 0.f);
            o6 = fmaxf(d0*a0.z + d1*a1.z + d2*a2.z + d3*a3.z + ab.z, 0.f);
            o7 = fmaxf(d0*a0.w + d1*a1.w + d2*a2.w + d3*a3.w + ab.w, 0.f);
        }
        bf16x8 aF = { (bf16_t)o0, (bf16_t)o1, (bf16_t)o2, (bf16_t)o3,
                      (bf16_t)o4, (bf16_t)o5, (bf16_t)o6, (bf16_t)o7 };
        int s = 4 + sp;
#pragma unroll
        for (int t = 0; t < 8; ++t) {
            bf16x8 bF = *(const bf16x8*)&swC1[(size_t)((t*8 + s)*64 + lane)*8];
            acc[t] = __builtin_amdgcn_mfma_f32_16x16x32_bf16(aF, bF, acc[t], 0, 0, 0);
        }
    }
    // cfeat slices: K in [0,128) -> s = 0..3, data already in registers
#pragma unroll
    for (int s = 0; s < 4; ++s) {
        float4 v0 = p[2*s], v1 = p[2*s+1];
        bf16x8 aF = { (bf16_t)v0.x, (bf16_t)v0.y, (bf16_t)v0.z, (bf16_t)v0.w,
                      (bf16_t)v1.x, (bf16_t)v1.y, (bf16_t)v1.z, (bf16_t)v1.w };
#pragma unroll
        for (int t = 0; t < 8; ++t) {
            bf16x8 bF = *(const bf16x8*)&swC1[(size_t)((t*8 + s)*64 + lane)*8];
            acc[t] = __builtin_amdgcn_mfma_f32_16x16x32_bf16(aF, bF, acc[t], 0, 0, 0);
        }
    }
    gn_rows(acc, lane, g_ctx, be_ctx, true);

    // restage h into per-wave LDS: row = g*4+rr, col = t*16 + r  (conflict-free)
#pragma unroll
    for (int t = 0; t < 8; ++t)
#pragma unroll
        for (int rr = 0; rr < 4; ++rr)
            sH[wave][(g*4 + rr)*136 + t*16 + r] = (bf16_t)acc[t][rr];

    // write-out: 4 lanes per row; one slot-claim atomic per edge
    int r2 = lane >> 2, c2 = lane & 3;
    int e2 = tb + r2;
    bool ev2 = e2 < E;
    int dst = 0;
    if (ev2 && c2 == 0) {
        int t2 = wi[e2];
        dst = off[t2] + atomicAdd(&cur[t2], 1);
    }
    dst = __shfl(dst, lane & ~3);
    if (ev2) {
        bf16_t* hp = hbuf + (size_t)dst * 128 + c2 * 32;
#pragma unroll
        for (int i = 0; i < 4; ++i)
            *(bf16x8*)(hp + i*8) = *(const bf16x8*)&sH[wave][r2*136 + c2*32 + i*8];
    }
}

// ---------------------------------------------------------------------------
// K3 (v3b): round-4 verified barrier-free structure, natural register budget.
// All 8 tfeat loads issued BEFORE the bin gather-sum (gather covers latency).
//   tf = tfeat@W_in + (sum of binned h rows)@W_ctx2   (fused MFMA chain)
//   out = relu(GN(relu(GN(relu(GN(tf)) @ W_m1)) @ W_m2) + tfeat)
// ---------------------------------------------------------------------------
__global__ __launch_bounds__(256) void k_out3(
    const float* __restrict__ tfeat, const bf16_t* __restrict__ hbuf,
    const int* __restrict__ off,
    const float* __restrict__ g_n, const float* __restrict__ be_n,
    const float* __restrict__ g_m1, const float* __restrict__ be_m1,
    const float* __restrict__ g_m2, const float* __restrict__ be_m2,
    const bf16_t* __restrict__ swIn, const bf16_t* __restrict__ swC2,
    const bf16_t* __restrict__ swM1, const bf16_t* __restrict__ swM2,
    float* __restrict__ out, int Nt)
{
    __shared__ alignas(16) bf16_t sB[4][2176];   // per-wave [16][136] bf16
    int tid = threadIdx.x, lane = tid & 63, wave = tid >> 6;
    int tb = (blockIdx.x*4 + wave)*16;
    int r = lane & 15, g = lane >> 4;
    int grow = tb + r;
    bool rv = grow < Nt;
    int rclamp = rv ? grow : (Nt - 1);

    // issue ALL tfeat loads up front (covered by the bin gather below)
    const float4* cf = (const float4*)(tfeat + (size_t)rclamp * 128);
    float4 p[8];
#pragma unroll
    for (int s = 0; s < 4; ++s) {
        p[2*s]   = cf[s*8 + g*2];
        p[2*s+1] = cf[s*8 + g*2 + 1];
    }

    // ---- bin gather-sum straight into this lane's A-frag cols {s*32+g*8..+8}
    float sums[32];
#pragma unroll
    for (int i = 0; i < 32; ++i) sums[i] = 0.f;
    int jb = rv ? off[grow] : 0, je = rv ? off[grow+1] : 0;
    for (int jr = jb; jr < je; ++jr) {
        const bf16_t* hp = hbuf + (size_t)jr*128 + g*8;
#pragma unroll
        for (int s = 0; s < 4; ++s) {
            bf16x8 hv = *(const bf16x8*)(hp + s*32);
#pragma unroll
            for (int q = 0; q < 8; ++q) sums[s*8+q] += (float)hv[q];
        }
    }
    // spill Hsum A-frags to per-wave LDS (frees 32 f32 regs; lane-local data)
#pragma unroll
    for (int s = 0; s < 4; ++s) {
        bf16x8 ah = { (bf16_t)sums[s*8+0], (bf16_t)sums[s*8+1],
                      (bf16_t)sums[s*8+2], (bf16_t)sums[s*8+3],
                      (bf16_t)sums[s*8+4], (bf16_t)sums[s*8+5],
                      (bf16_t)sums[s*8+6], (bf16_t)sums[s*8+7] };
        *(bf16x8*)&sB[wave][r*136 + s*32 + g*8] = ah;
    }

    // ---- gemm1: acc = tfeat@W_in + Hsum@W_ctx2  (s-outer; data in regs/LDS)
    floatx4 acc[8];
#pragma unroll
    for (int t = 0; t < 8; ++t) acc[t] = (floatx4){0.f,0.f,0.f,0.f};
#pragma unroll
    for (int s = 0; s < 4; ++s) {
        bf16x8 aH = *(const bf16x8*)&sB[wave][r*136 + s*32 + g*8];
#pragma unroll
        for (int t = 0; t < 8; ++t) {
            bf16x8 bF = *(const bf16x8*)&swC2[((t*4+s)*64 + lane)*8];
            acc[t] = __builtin_amdgcn_mfma_f32_16x16x32_bf16(aH, bF, acc[t], 0, 0, 0);
        }
        float4 v0 = p[2*s], v1 = p[2*s+1];
        bf16x8 aF = { (bf16_t)v0.x, (bf16_t)v0.y, (bf16_t)v0.z, (bf16_t)v0.w,
                      (bf16_t)v1.x, (bf16_t)v1.y, (bf16_t)v1.z, (bf16_t)v1.w };
#pragma unroll
        for (int t = 0; t < 8; ++t) {
            bf16x8 bF = *(const bf16x8*)&swIn[((t*4+s)*64 + lane)*8];
            acc[t] = __builtin_amdgcn_mfma_f32_16x16x32_bf16(aF, bF, acc[t], 0, 0, 0);
        }
    }
    gn_rows(acc, lane, g_n, be_n, true);

    // ---- restage -> gemm2 (W_m1)
#pragma unroll
    for (int t = 0; t < 8; ++t)
#pragma unroll
        for (int rr = 0; rr < 4; ++rr)
            sB[wave][(g*4 + rr)*136 + t*16 + r] = (bf16_t)acc[t][rr];
#pragma unroll
    for (int t = 0; t < 8; ++t) acc[t] = (floatx4){0.f,0.f,0.f,0.f};
#pragma unroll
    for (int s = 0; s < 4; ++s) {
        bf16x8 aF = *(const bf16x8*)&sB[wave][r*136 + s*32 + g*8];
#pragma unroll
        for (int t = 0; t < 8; ++t) {
            bf16x8 bF = *(const bf16x8*)&swM1[((t*4+s)*64 + lane)*8];
            acc[t] = __builtin_amdgcn_mfma_f32_16x16x32_bf16(aF, bF, acc[t], 0, 0, 0);
        }
    }
    gn_rows(acc, lane, g_m1, be_m1, true);

    // ---- restage -> gemm3 (W_m2)
#pragma unroll
    for (int t = 0; t < 8; ++t)
#pragma unroll
        for (int rr = 0; rr < 4; ++rr)
            sB[wave][(g*4 + rr)*136 + t*16 + r] = (bf16_t)acc[t][rr];
#pragma unroll
    for (int t = 0; t < 8; ++t) acc[t] = (floatx4){0.f,0.f,0.f,0.f};
#pragma unroll
    for (int s = 0; s < 4; ++s) {
        bf16x8 aF = *(const bf16x8*)&sB[wave][r*136 + s*32 + g*8];
#pragma unroll
        for (int t = 0; t < 8; ++t) {
            bf16x8 bF = *(const bf16x8*)&swM2[((t*4+s)*64 + lane)*8];
            acc[t] = __builtin_amdgcn_mfma_f32_16x16x32_bf16(aF, bF, acc[t], 0, 0, 0);
        }
    }
    gn_rows(acc, lane, g_m2, be_m2, false);

    // ---- epilogue: +identity, relu, direct C-layout stores (64B segments)
#pragma unroll
    for (int t = 0; t < 8; ++t) {
        int n = t*16 + r;
#pragma unroll
        for (int rr = 0; rr < 4; ++rr) {
            int row = tb + g*4 + rr;
            if (row < Nt) {
                float v = acc[t][rr] + tfeat[(size_t)row*128 + n];
                out[(size_t)row*128 + n] = fmaxf(v, 0.f);
            }
        }
    }
}

// ===========================================================================
// FALLBACK PATH (previous kernels, used only if workspace is too small for
// the binned h buffer).
// ===========================================================================
__global__ __launch_bounds__(256) void k_gemm_in(
    const float* __restrict__ tfeat, const bf16_t* __restrict__ swW,
    float* __restrict__ tf, int Nt)
{
    __shared__ alignas(16) bf16_t sA[4][2048];
    int tid = threadIdx.x, lane = tid & 63, wave = tid >> 6;

    int tb = (blockIdx.x * 4 + wave) * 16;
    int r = lane >> 2, cb = (lane & 3) * 32;
    int grow = tb + r;
    bool rv = grow < Nt;
    const float4* src = (const float4*)(tfeat + (size_t)(rv ? grow : 0) * 128 + cb);
#pragma unroll
    for (int i = 0; i < 8; ++i) {
        float4 v = rv ? src[i] : make_float4(0.f,0.f,0.f,0.f);
        int k = cb + 4*i;
        int s = k >> 5, q = (k >> 3) & 3, j = k & 7;
        bf16x4 pk = { (bf16_t)v.x, (bf16_t)v.y, (bf16_t)v.z, (bf16_t)v.w };
        *(bf16x4*)&sA[wave][(s*64 + q*16 + r)*8 + j] = pk;
    }
    __syncthreads();
    int m = lane & 15, g = lane >> 4;
    bf16x8 aF[4];
#pragma unroll
    for (int s = 0; s < 4; ++s) aF[s] = *(const bf16x8*)&sA[wave][(s*64 + lane)*8];
#pragma unroll
    for (int t = 0; t < 8; ++t) {
        floatx4 a = {0.f,0.f,0.f,0.f};
#pragma unroll
        for (int s = 0; s < 4; ++s) {
            bf16x8 bF = *(const bf16x8*)&swW[((t*4+s)*64 + lane)*8];
            a = __builtin_amdgcn_mfma_f32_16x16x32_bf16(aF[s], bF, a, 0, 0, 0);
        }
#pragma unroll
        for (int rr = 0; rr < 4; ++rr) {
            int row = tb + g*4 + rr;
            if (row < Nt) tf[(size_t)row*128 + t*16 + m] = a[rr];
        }
    }
}

__global__ __launch_bounds__(256) void k_edge_old(
    const float* __restrict__ cfeat, const float* __restrict__ cpose,
    const float* __restrict__ tpose, const int* __restrict__ hi,
    const int* __restrict__ wi, const float* __restrict__ W_rp,
    const float* __restrict__ b_rp, const float* __restrict__ g_ctx,
    const float* __restrict__ be_ctx, const bf16_t* __restrict__ swC1,
    const bf16_t* __restrict__ swC2, float* __restrict__ tf, int E)
{
    __shared__ alignas(16) bf16_t sA[4][4096];
    int tid = threadIdx.x, lane = tid & 63, wave = tid >> 6;

    int tb = (blockIdx.x * 4 + wave) * 16;
    int r = lane >> 2, cb = (lane & 3) * 32;
    int e = min(tb + r, E - 1);
    int ci = hi[e], ti = wi[e];
    const float4* src = (const float4*)(cfeat + (size_t)ci * 128 + cb);
#pragma unroll
    for (int i = 0; i < 8; ++i) {
        float4 v = src[i];
        int k = cb + 4*i;
        int s = k >> 5, q = (k >> 3) & 3, j = k & 7;
        bf16x4 pk = { (bf16_t)v.x, (bf16_t)v.y, (bf16_t)v.z, (bf16_t)v.w };
        *(bf16x4*)&sA[wave][(s*64 + q*16 + r)*8 + j] = pk;
    }
    float4 cp = ((const float4*)cpose)[ci];
    float4 tp = ((const float4*)tpose)[ti];
    float d0 = cp.x - tp.x, d1 = cp.y - tp.y, d2 = cp.z - tp.z, d3 = cp.w - tp.w;
#pragma unroll
    for (int i = 0; i < 8; ++i) {
        int cc = cb + 4*i;
        float4 w0 = *(const float4*)(W_rp + cc);
        float4 w1 = *(const float4*)(W_rp + 128 + cc);
        float4 w2 = *(const float4*)(W_rp + 256 + cc);
        float4 w3 = *(const float4*)(W_rp + 384 + cc);
        float4 bb = *(const float4*)(b_rp + cc);
        float o0 = fmaxf(d0*w0.x + d1*w1.x + d2*w2.x + d3*w3.x + bb.x, 0.f);
        float o1 = fmaxf(d0*w0.y + d1*w1.y + d2*w2.y + d3*w3.y + bb.y, 0.f);
        float o2 = fmaxf(d0*w0.z + d1*w1.z + d2*w2.z + d3*w3.z + bb.z, 0.f);
        float o3 = fmaxf(d0*w0.w + d1*w1.w + d2*w2.w + d3*w3.w + bb.w, 0.f);
        int k = 128 + cc;
        int s = k >> 5, q = (k >> 3) & 3, j = k & 7;
        bf16x4 pk = { (bf16_t)o0, (bf16_t)o1, (bf16_t)o2, (bf16_t)o3 };
        *(bf16x4*)&sA[wave][(s*64 + q*16 + r)*8 + j] = pk;
    }
    __syncthreads();

    int m = lane & 15, g = lane >> 4;
    bf16x8 aF[8];
#pragma unroll
    for (int s = 0; s < 8; ++s) aF[s] = *(const bf16x8*)&sA[wave][(s*64 + lane)*8];
    floatx4 acc[8];
#pragma unroll
    for (int t = 0; t < 8; ++t) {
        floatx4 a = {0.f,0.f,0.f,0.f};
#pragma unroll
        for (int s = 0; s < 8; ++s) {
            bf16x8 bF = *(const bf16x8*)&swC1[(size_t)((t*8+s)*64 + lane)*8];
            a = __builtin_amdgcn_mfma_f32_16x16x32_bf16(aF[s], bF, a, 0, 0, 0);
        }
        acc[t] = a;
    }
    gn_rows(acc, lane, g_ctx, be_ctx, true);
    __syncthreads();
#pragma unroll
    for (int t = 0; t < 8; ++t) {
        int n = t*16 + m;
        int s = n >> 5, q = (n >> 3) & 3, j = n & 7;
#pragma unroll
        for (int rr = 0; rr < 4; ++rr)
            sA[wave][(s*64 + q*16 + (g*4+rr))*8 + j] = (bf16_t)acc[t][rr];
    }
    __syncthreads();
    bf16x8 aF2[4];
#pragma unroll
    for (int s = 0; s < 4; ++s) aF2[s] = *(const bf16x8*)&sA[wave][(s*64 + lane)*8];
    int dstrow[4]; bool vald[4];
#pragma unroll
    for (int rr = 0; rr < 4; ++rr) {
        int ee = tb + g*4 + rr;
        vald[rr] = ee < E;
        dstrow[rr] = vald[rr] ? wi[ee] : 0;
    }
#pragma unroll
    for (int t = 0; t < 8; ++t) {
        floatx4 a = {0.f,0.f,0.f,0.f};
#pragma unroll
        for (int s = 0; s < 4; ++s) {
            bf16x8 bF = *(const bf16x8*)&swC2[((t*4+s)*64 + lane)*8];
            a = __builtin_amdgcn_mfma_f32_16x16x32_bf16(aF2[s], bF, a, 0, 0, 0);
        }
#pragma unroll
        for (int rr = 0; rr < 4; ++rr) {
            if (vald[rr])
                atomicAdd(&tf[(size_t)dstrow[rr]*128 + t*16 + m], a[rr]);
        }
    }
}

__global__ __launch_bounds__(256) void k_out_old(
    const float* __restrict__ tf, const float* __restrict__ identity,
    const float* __restrict__ g_n, const float* __restrict__ be_n,
    const float* __restrict__ g_m1, const float* __restrict__ be_m1,
    const float* __restrict__ g_m2, const float* __restrict__ be_m2,
    const bf16_t* __restrict__ swM1, const bf16_t* __restrict__ swM2,
    float* __restrict__ out, int Nt)
{
    __shared__ alignas(16) bf16_t sA[4][2048];
    int tid = threadIdx.x, lane = tid & 63, wave = tid >> 6;

    int tb = (blockIdx.x*4 + wave)*16;
    int r = lane >> 2, cb = (lane & 3)*32;
    int grow = tb + r;
    bool rv = grow < Nt;
    const float4* src = (const float4*)(tf + (size_t)(rv ? grow : 0)*128 + cb);
    float vals[32];
    float ls = 0.f, lq = 0.f;
#pragma unroll
    for (int i = 0; i < 8; ++i) {
        float4 v = rv ? src[i] : make_float4(0.f,0.f,0.f,0.f);
        vals[4*i+0]=v.x; vals[4*i+1]=v.y; vals[4*i+2]=v.z; vals[4*i+3]=v.w;
        ls += v.x+v.y+v.z+v.w;
        lq += v.x*v.x+v.y*v.y+v.z*v.z+v.w*v.w;
    }
    ls += __shfl_xor(ls,1); lq += __shfl_xor(lq,1);
    ls += __shfl_xor(ls,2); lq += __shfl_xor(lq,2);
    float mean = ls*(1.f/128.f);
    float inv = rsqrtf(lq*(1.f/128.f) - mean*mean + EPSF);
#pragma unroll
    for (int i = 0; i < 8; ++i) {
        int cc = cb + 4*i;
        float4 ga = *(const float4*)(g_n + cc);
        float4 be = *(const float4*)(be_n + cc);
        float o0 = fmaxf((vals[4*i+0]-mean)*inv*ga.x + be.x, 0.f);
        float o1 = fmaxf((vals[4*i+1]-mean)*inv*ga.y + be.y, 0.f);
        float o2 = fmaxf((vals[4*i+2]-mean)*inv*ga.z + be.z, 0.f);
        float o3 = fmaxf((vals[4*i+3]-mean)*inv*ga.w + be.w, 0.f);
        int s = cc >> 5, q = (cc >> 3) & 3, j = cc & 7;
        bf16x4 pk = { (bf16_t)o0, (bf16_t)o1, (bf16_t)o2, (bf16_t)o3 };
        *(bf16x4*)&sA[wave][(s*64 + q*16 + r)*8 + j] = pk;
    }
    __syncthreads();
    int m = lane & 15, g = lane >> 4;
    bf16x8 aF[4];
#pragma unroll
    for (int s = 0; s < 4; ++s) aF[s] = *(const bf16x8*)&sA[wave][(s*64 + lane)*8];
    floatx4 acc[8];
#pragma unroll
    for (int t = 0; t < 8; ++t) {
        floatx4 a = {0.f,0.f,0.f,0.f};
#pragma unroll
        for (int s = 0; s < 4; ++s) {
            bf16x8 bF = *(const bf16x8*)&swM1[((t*4+s)*64 + lane)*8];
            a = __builtin_amdgcn_mfma_f32_16x16x32_bf16(aF[s], bF, a, 0, 0, 0);
        }
        acc[t] = a;
    }
    gn_rows(acc, lane, g_m1, be_m1, true);
    __syncthreads();
#pragma unroll
    for (int t = 0; t < 8; ++t) {
        int n = t*16 + m;
        int s = n >> 5, q = (n >> 3) & 3, j = n & 7;
#pragma unroll
        for (int rr = 0; rr < 4; ++rr)
            sA[wave][(s*64 + q*16 + (g*4+rr))*8 + j] = (bf16_t)acc[t][rr];
    }
    __syncthreads();
#pragma unroll
    for (int s = 0; s < 4; ++s) aF[s] = *(const bf16x8*)&sA[wave][(s*64 + lane)*8];
#pragma unroll
    for (int t = 0; t < 8; ++t) {
        floatx4 a = {0.f,0.f,0.f,0.f};
#pragma unroll
        for (int s = 0; s < 4; ++s) {
            bf16x8 bF = *(const bf16x8*)&swM2[((t*4+s)*64 + lane)*8];
            a = __builtin_amdgcn_mfma_f32_16x16x32_bf16(aF[s], bF, a, 0, 0, 0);
        }
        acc[t] = a;
    }
    gn_rows(acc, lane, g_m2, be_m2, false);
#pragma unroll
    for (int t = 0; t < 8; ++t) {
        int n = t*16 + m;
#pragma unroll
        for (int rr = 0; rr < 4; ++rr) {
            int row = tb + g*4 + rr;
            if (row < Nt) {
                float v = acc[t][rr] + identity[(size_t)row*128 + n];
                out[(size_t)row*128 + n] = fmaxf(v, 0.f);
            }
        }
    }
}

// ---------------------------------------------------------------------------
extern "C" void kernel_launch(void* const* d_in, const int* in_sizes, int n_in,
                              void* d_out, int out_size, void* d_ws, size_t ws_size,
                              hipStream_t stream)
{
    const float* cfeat  = (const float*)d_in[0];
    const float* tfeat  = (const float*)d_in[1];
    const float* cpose  = (const float*)d_in[2];
    const float* tpose  = (const float*)d_in[3];
    const int*   hi     = (const int*)d_in[4];
    const int*   wi     = (const int*)d_in[5];
    const float* W_in   = (const float*)d_in[6];
    const float* W_rp   = (const float*)d_in[7];
    const float* b_rp   = (const float*)d_in[8];
    const float* W_ctx1 = (const float*)d_in[9];
    const float* g_ctx  = (const float*)d_in[10];
    const float* be_ctx = (const float*)d_in[11];
    const float* W_ctx2 = (const float*)d_in[12];
    const float* g_n    = (const float*)d_in[13];
    const float* be_n   = (const float*)d_in[14];
    const float* W_m1   = (const float*)d_in[15];
    const float* g_m1   = (const float*)d_in[16];
    const float* be_m1  = (const float*)d_in[17];
    const float* W_m2   = (const float*)d_in[18];
    const float* g_m2   = (const float*)d_in[19];
    const float* be_m2  = (const float*)d_in[20];

    int Nt = in_sizes[1] / 128;
    int E  = in_sizes[4];
    float* outp = (float*)d_out;

    // new-path workspace layout
    char* base = (char*)d_ws;
    size_t o = 98304 * sizeof(bf16_t);                 // sw @ 0
    o = (o + 255) & ~(size_t)255;
    size_t o_cnt = o; o += (size_t)Nt * 4;
    o = (o + 255) & ~(size_t)255;
    size_t o_off = o; o += ((size_t)Nt + 1) * 4;
    o = (o + 255) & ~(size_t)255;
    size_t o_cur = o; o += (size_t)Nt * 4;
    o = (o + 255) & ~(size_t)255;
    size_t o_h = o; o += (size_t)E * 128 * sizeof(bf16_t);

    if (ws_size >= o) {
        bf16_t* sw   = (bf16_t*)base;
        int*    cnt  = (int*)(base + o_cnt);
        int*    off  = (int*)(base + o_off);
        int*    cur  = (int*)(base + o_cur);
        bf16_t* hbuf = (bf16_t*)(base + o_h);
        bf16_t* swIn = sw;
        bf16_t* swC1 = sw + 16384;
        bf16_t* swC2 = sw + 49152;
        bf16_t* swM1 = sw + 65536;
        bf16_t* swM2 = sw + 81920;

        hipMemsetAsync(cnt, 0, (size_t)Nt * 4, stream);
        hipMemsetAsync(cur, 0, (size_t)Nt * 4, stream);
        k_prep<<<384, 256, 0, stream>>>(W_in, W_ctx1, W_ctx2, W_m1, W_m2, sw);
        k_count<<<(E + 255) / 256, 256, 0, stream>>>(wi, cnt, E);
        k_scan<<<1, 1024, 0, stream>>>(cnt, off, Nt);
        k_edge5<<<(E + 63) / 64, 256, 0, stream>>>(cfeat, cpose, tpose, hi, wi,
                                                   W_rp, b_rp, g_ctx, be_ctx,
                                                   swC1, off, cur, hbuf, E);
        k_out3<<<(Nt + 63) / 64, 256, 0, stream>>>(tfeat, hbuf, off,
                                                   g_n, be_n, g_m1, be_m1,
                                                   g_m2, be_m2,
                                                   swIn, swC2, swM1, swM2,
                                                   outp, Nt);
    } else {
        // fallback: previous atomic-scatter path
        float*  tf = (float*)d_ws;                                   // [Nt,128] f32
        bf16_t* sw = (bf16_t*)((char*)d_ws + (size_t)Nt * 128 * sizeof(float));
        bf16_t* swIn = sw;
        bf16_t* swC1 = sw + 16384;
        bf16_t* swC2 = sw + 49152;
        bf16_t* swM1 = sw + 65536;
        bf16_t* swM2 = sw + 81920;

        k_prep<<<384, 256, 0, stream>>>(W_in, W_ctx1, W_ctx2, W_m1, W_m2, sw);
        k_gemm_in<<<(Nt + 63) / 64, 256, 0, stream>>>(tfeat, swIn, tf, Nt);
        k_edge_old<<<(E + 63) / 64, 256, 0, stream>>>(cfeat, cpose, tpose, hi, wi,
                                                      W_rp, b_rp, g_ctx, be_ctx,
                                                      swC1, swC2, tf, E);
        k_out_old<<<(Nt + 63) / 64, 256, 0, stream>>>(tf, tfeat, g_n, be_n,
                                                      g_m1, be_m1, g_m2, be_m2,
                                                      swM1, swM2, outp, Nt);
    }
}

// Round 6
// 480.410 us; speedup vs baseline: 1.6954x; 1.0095x over previous
//
#include <hip/hip_runtime.h>

typedef __bf16 bf16_t;
typedef bf16_t bf16x4 __attribute__((ext_vector_type(4)));
typedef bf16_t bf16x8 __attribute__((ext_vector_type(8)));
typedef float floatx4 __attribute__((ext_vector_type(4)));

#define EPSF 1e-5f
#define DEV static __device__ __forceinline__

// ---------------------------------------------------------------------------
// K0: swizzle weight matrices (f32 [K][128]) into B-fragment order, bf16.
// sw[((t*nK + s)*64 + l)*8 + j] = W[(s*32 + (l>>4)*8 + j)*128 + (t*16 + (l&15))]
// Layout ranges (bf16 elems): W_in@0(16384), W_ctx1@16384(32768),
// W_ctx2@49152(16384), W_m1@65536(16384), W_m2@81920(16384). Total 98304.
// ---------------------------------------------------------------------------
__global__ __launch_bounds__(256) void k_prep(
    const float* __restrict__ W_in, const float* __restrict__ W_ctx1,
    const float* __restrict__ W_ctx2, const float* __restrict__ W_m1,
    const float* __restrict__ W_m2, bf16_t* __restrict__ sw)
{
    int idx = blockIdx.x * 256 + threadIdx.x;   // grid sized to exactly 98304
    const float* W; int base, ks;
    if (idx < 16384)      { W = W_in;   base = 0;     ks = 2; }
    else if (idx < 49152) { W = W_ctx1; base = 16384; ks = 3; }
    else if (idx < 65536) { W = W_ctx2; base = 49152; ks = 2; }
    else if (idx < 81920) { W = W_m1;   base = 65536; ks = 2; }
    else                  { W = W_m2;   base = 81920; ks = 2; }
    int local = idx - base;
    int j = local & 7, l = (local >> 3) & 63, rest = local >> 9;
    int s = rest & ((1 << ks) - 1), t = rest >> ks;
    int k = s * 32 + (l >> 4) * 8 + j;
    int n = t * 16 + (l & 15);
    sw[idx] = (bf16_t)W[k * 128 + n];
}

// GroupNorm over 128 channels per row, operating on MFMA C-layout accumulators.
// acc[t][rr] holds element (row = (lane>>4)*4+rr, col = t*16 + (lane&15)).
DEV void gn_rows(floatx4* acc, int lane, const float* __restrict__ gamma,
                 const float* __restrict__ beta, bool do_relu)
{
    int m = lane & 15;
    float s1[4] = {0.f,0.f,0.f,0.f}, s2[4] = {0.f,0.f,0.f,0.f};
#pragma unroll
    for (int t = 0; t < 8; ++t)
#pragma unroll
        for (int rr = 0; rr < 4; ++rr) { float v = acc[t][rr]; s1[rr] += v; s2[rr] += v*v; }
#pragma unroll
    for (int mask = 1; mask <= 8; mask <<= 1)
#pragma unroll
        for (int rr = 0; rr < 4; ++rr) {
            s1[rr] += __shfl_xor(s1[rr], mask);
            s2[rr] += __shfl_xor(s2[rr], mask);
        }
    float mean[4], inv[4];
#pragma unroll
    for (int rr = 0; rr < 4; ++rr) {
        mean[rr] = s1[rr] * (1.f/128.f);
        float var = s2[rr] * (1.f/128.f) - mean[rr]*mean[rr];
        inv[rr] = rsqrtf(var + EPSF);
    }
#pragma unroll
    for (int t = 0; t < 8; ++t) {
        int n = t*16 + m;
        float ga = gamma[n], be = beta[n];
#pragma unroll
        for (int rr = 0; rr < 4; ++rr) {
            float v = (acc[t][rr] - mean[rr]) * inv[rr] * ga + be;
            acc[t][rr] = do_relu ? fmaxf(v, 0.f) : v;
        }
    }
}

// ---------------------------------------------------------------------------
// Binning: histogram of wi, exclusive scan -> off[Nt+1].
// ---------------------------------------------------------------------------
__global__ __launch_bounds__(256) void k_count(const int* __restrict__ wi,
                                               int* __restrict__ cnt, int E)
{
    int e = blockIdx.x * 256 + threadIdx.x;
    if (e < E) atomicAdd(&cnt[wi[e]], 1);
}

__global__ __launch_bounds__(1024) void k_scan(const int* __restrict__ cnt,
                                               int* __restrict__ off, int Nt)
{
    __shared__ int wsum[16];
    __shared__ int s_carry;
    int tid = threadIdx.x, lane = tid & 63, wid = tid >> 6;
    if (tid == 0) s_carry = 0;
    __syncthreads();
    for (int bs = 0; bs < Nt; bs += 4096) {
        int i0 = bs + tid * 4;
        int v0 = 0, v1 = 0, v2 = 0, v3 = 0;
        if (i0 + 3 < Nt) {
            int4 v = *(const int4*)(cnt + i0);
            v0 = v.x; v1 = v.y; v2 = v.z; v3 = v.w;
        } else {
            if (i0     < Nt) v0 = cnt[i0];
            if (i0 + 1 < Nt) v1 = cnt[i0+1];
            if (i0 + 2 < Nt) v2 = cnt[i0+2];
            if (i0 + 3 < Nt) v3 = cnt[i0+3];
        }
        int tot = v0 + v1 + v2 + v3;
        int x = tot;
#pragma unroll
        for (int d = 1; d < 64; d <<= 1) {
            int y = __shfl_up(x, d);
            if (lane >= d) x += y;
        }
        if (lane == 63) wsum[wid] = x;
        __syncthreads();
        if (wid == 0) {
            int wv = (lane < 16) ? wsum[lane] : 0;
#pragma unroll
            for (int d = 1; d < 16; d <<= 1) {
                int y = __shfl_up(wv, d);
                if (lane >= d) wv += y;
            }
            if (lane < 16) wsum[lane] = wv;
        }
        __syncthreads();
        int ebase = s_carry + ((wid > 0) ? wsum[wid-1] : 0) + (x - tot);
        if (i0 + 3 < Nt) {
            *(int4*)(off + i0) = make_int4(ebase, ebase+v0, ebase+v0+v1, ebase+v0+v1+v2);
        } else {
            if (i0     < Nt) off[i0]   = ebase;
            if (i0 + 1 < Nt) off[i0+1] = ebase + v0;
            if (i0 + 2 < Nt) off[i0+2] = ebase + v0 + v1;
            if (i0 + 3 < Nt) off[i0+3] = ebase + v0 + v1 + v2;
        }
        __syncthreads();
        if (tid == 0) s_carry += wsum[15];
        __syncthreads();
    }
    if (tid == 0) off[Nt] = s_carry;
}

// ---------------------------------------------------------------------------
// K2 (v6): TWO M-tiles per wave (32 edges) so each B-fragment load feeds two
// MFMAs (B-reuse 1 -> 2), plus slot-claim atomics hoisted to kernel entry so
// their latency overlaps the GEMM. Barrier-free; verified fragment layouts
// and [16][136] restage reused; restage/write-out runs twice sequentially on
// the same per-wave LDS (same-wave in-order DS semantics).
// ---------------------------------------------------------------------------
__global__ __launch_bounds__(256) void k_edge6(
    const float* __restrict__ cfeat, const float* __restrict__ cpose,
    const float* __restrict__ tpose, const int* __restrict__ hi,
    const int* __restrict__ wi, const float* __restrict__ W_rp,
    const float* __restrict__ b_rp, const float* __restrict__ g_ctx,
    const float* __restrict__ be_ctx, const bf16_t* __restrict__ swC1,
    const int* __restrict__ off, int* __restrict__ cur,
    bf16_t* __restrict__ hbuf, int E)
{
    __shared__ alignas(16) bf16_t sH[4][2176];   // per-wave [16][136] bf16
    int tid = threadIdx.x, lane = tid & 63, wave = tid >> 6;
    int tb = (blockIdx.x * 4 + wave) * 32;
    int r = lane & 15, g = lane >> 4;
    int e0 = min(tb + r, E - 1);
    int e1 = min(tb + 16 + r, E - 1);
    int ci0 = hi[e0], ti0 = wi[e0];
    int ci1 = hi[e1], ti1 = wi[e1];

    // ---- early slot claims: atomic latency overlaps the whole GEMM below
    int r2 = lane >> 2, c2 = lane & 3;
    int ea = tb + r2, eb = tb + 16 + r2;
    bool eva = ea < E, evb = eb < E;
    int dst0 = 0, dst1 = 0;
    if (c2 == 0) {
        if (eva) { int t2 = wi[ea]; dst0 = off[t2] + atomicAdd(&cur[t2], 1); }
        if (evb) { int t2 = wi[eb]; dst1 = off[t2] + atomicAdd(&cur[t2], 1); }
    }
    dst0 = __shfl(dst0, lane & ~3);
    dst1 = __shfl(dst1, lane & ~3);

    floatx4 acc0[8], acc1[8];
#pragma unroll
    for (int t = 0; t < 8; ++t) {
        acc0[t] = (floatx4){0.f,0.f,0.f,0.f};
        acc1[t] = (floatx4){0.f,0.f,0.f,0.f};
    }

    // ---- 2-deep cfeat prefetch for both tiles (s=0,1 in flight)
    const float4* cf0 = (const float4*)(cfeat + (size_t)ci0 * 128);
    const float4* cf1 = (const float4*)(cfeat + (size_t)ci1 * 128);
    float4 t0b[2][2], t1b[2][2];
    t0b[0][0] = cf0[g*2];     t0b[0][1] = cf0[g*2 + 1];
    t1b[0][0] = cf1[g*2];     t1b[0][1] = cf1[g*2 + 1];
    t0b[1][0] = cf0[8 + g*2]; t0b[1][1] = cf0[8 + g*2 + 1];
    t1b[1][0] = cf1[8 + g*2]; t1b[1][1] = cf1[8 + g*2 + 1];

    // ---- relpose MLP slices: K in [128,256) -> s = 4..7 (covers prefetch)
    float4 cp0 = ((const float4*)cpose)[ci0];
    float4 tp0 = ((const float4*)tpose)[ti0];
    float4 cp1 = ((const float4*)cpose)[ci1];
    float4 tp1 = ((const float4*)tpose)[ti1];
    float d00 = cp0.x - tp0.x, d01 = cp0.y - tp0.y, d02 = cp0.z - tp0.z, d03 = cp0.w - tp0.w;
    float d10 = cp1.x - tp1.x, d11 = cp1.y - tp1.y, d12 = cp1.z - tp1.z, d13 = cp1.w - tp1.w;
#pragma unroll
    for (int sp = 0; sp < 4; ++sp) {
        int k0 = sp * 32 + g * 8;
        const float4* w0 = (const float4*)(W_rp + k0);
        const float4* w1 = (const float4*)(W_rp + 128 + k0);
        const float4* w2 = (const float4*)(W_rp + 256 + k0);
        const float4* w3 = (const float4*)(W_rp + 384 + k0);
        const float4* bb = (const float4*)(b_rp + k0);
        float o0[8], o1[8];
#pragma unroll
        for (int h = 0; h < 2; ++h) {
            float4 a0 = w0[h], a1 = w1[h], a2 = w2[h], a3 = w3[h], ab = bb[h];
            o0[4*h+0] = fmaxf(d00*a0.x + d01*a1.x + d02*a2.x + d03*a3.x + ab.x, 0.f);
            o0[4*h+1] = fmaxf(d00*a0.y + d01*a1.y + d02*a2.y + d03*a3.y + ab.y, 0.f);
            o0[4*h+2] = fmaxf(d00*a0.z + d01*a1.z + d02*a2.z + d03*a3.z + ab.z, 0.f);
            o0[4*h+3] = fmaxf(d00*a0.w + d01*a1.w + d02*a2.w + d03*a3.w + ab.w, 0.f);
            o1[4*h+0] = fmaxf(d10*a0.x + d11*a1.x + d12*a2.x + d13*a3.x + ab.x, 0.f);
            o1[4*h+1] = fmaxf(d10*a0.y + d11*a1.y + d12*a2.y + d13*a3.y + ab.y, 0.f);
            o1[4*h+2] = fmaxf(d10*a0.z + d11*a1.z + d12*a2.z + d13*a3.z + ab.z, 0.f);
            o1[4*h+3] = fmaxf(d10*a0.w + d11*a1.w + d12*a2.w + d13*a3.w + ab.w, 0.f);
        }
        bf16x8 aF0 = { (bf16_t)o0[0], (bf16_t)o0[1], (bf16_t)o0[2], (bf16_t)o0[3],
                       (bf16_t)o0[4], (bf16_t)o0[5], (bf16_t)o0[6], (bf16_t)o0[7] };
        bf16x8 aF1 = { (bf16_t)o1[0], (bf16_t)o1[1], (bf16_t)o1[2], (bf16_t)o1[3],
                       (bf16_t)o1[4], (bf16_t)o1[5], (bf16_t)o1[6], (bf16_t)o1[7] };
        int s = 4 + sp;
#pragma unroll
        for (int t = 0; t < 8; ++t) {
            bf16x8 bF = *(const bf16x8*)&swC1[(size_t)((t*8 + s)*64 + lane)*8];
            acc0[t] = __builtin_amdgcn_mfma_f32_16x16x32_bf16(aF0, bF, acc0[t], 0, 0, 0);
            acc1[t] = __builtin_amdgcn_mfma_f32_16x16x32_bf16(aF1, bF, acc1[t], 0, 0, 0);
        }
    }
    // ---- cfeat slices: K in [0,128) -> s = 0..3, rolling 2-deep prefetch
#pragma unroll
    for (int s = 0; s < 4; ++s) {
        float4 v00 = t0b[s & 1][0], v01 = t0b[s & 1][1];
        float4 v10 = t1b[s & 1][0], v11 = t1b[s & 1][1];
        if (s < 2) {
            t0b[s & 1][0] = cf0[(s+2)*8 + g*2]; t0b[s & 1][1] = cf0[(s+2)*8 + g*2 + 1];
            t1b[s & 1][0] = cf1[(s+2)*8 + g*2]; t1b[s & 1][1] = cf1[(s+2)*8 + g*2 + 1];
        }
        bf16x8 aF0 = { (bf16_t)v00.x, (bf16_t)v00.y, (bf16_t)v00.z, (bf16_t)v00.w,
                       (bf16_t)v01.x, (bf16_t)v01.y, (bf16_t)v01.z, (bf16_t)v01.w };
        bf16x8 aF1 = { (bf16_t)v10.x, (bf16_t)v10.y, (bf16_t)v10.z, (bf16_t)v10.w,
                       (bf16_t)v11.x, (bf16_t)v11.y, (bf16_t)v11.z, (bf16_t)v11.w };
#pragma unroll
        for (int t = 0; t < 8; ++t) {
            bf16x8 bF = *(const bf16x8*)&swC1[(size_t)((t*8 + s)*64 + lane)*8];
            acc0[t] = __builtin_amdgcn_mfma_f32_16x16x32_bf16(aF0, bF, acc0[t], 0, 0, 0);
            acc1[t] = __builtin_amdgcn_mfma_f32_16x16x32_bf16(aF1, bF, acc1[t], 0, 0, 0);
        }
    }

    // ---- tile0: GN -> restage -> write-out
    gn_rows(acc0, lane, g_ctx, be_ctx, true);
#pragma unroll
    for (int t = 0; t < 8; ++t)
#pragma unroll
        for (int rr = 0; rr < 4; ++rr)
            sH[wave][(g*4 + rr)*136 + t*16 + r] = (bf16_t)acc0[t][rr];
    if (eva) {
        bf16_t* hp = hbuf + (size_t)dst0 * 128 + c2 * 32;
#pragma unroll
        for (int i = 0; i < 4; ++i)
            *(bf16x8*)(hp + i*8) = *(const bf16x8*)&sH[wave][r2*136 + c2*32 + i*8];
    }
    // ---- tile1: GN -> restage (same LDS, same-wave in-order) -> write-out
    gn_rows(acc1, lane, g_ctx, be_ctx, true);
#pragma unroll
    for (int t = 0; t < 8; ++t)
#pragma unroll
        for (int rr = 0; rr < 4; ++rr)
            sH[wave][(g*4 + rr)*136 + t*16 + r] = (bf16_t)acc1[t][rr];
    if (evb) {
        bf16_t* hp = hbuf + (size_t)dst1 * 128 + c2 * 32;
#pragma unroll
        for (int i = 0; i < 4; ++i)
            *(bf16x8*)(hp + i*8) = *(const bf16x8*)&sH[wave][r2*136 + c2*32 + i*8];
    }
}

// ---------------------------------------------------------------------------
// K3 (v3b): barrier-free, per-wave independent (unchanged from round 5).
// ---------------------------------------------------------------------------
__global__ __launch_bounds__(256) void k_out3(
    const float* __restrict__ tfeat, const bf16_t* __restrict__ hbuf,
    const int* __restrict__ off,
    const float* __restrict__ g_n, const float* __restrict__ be_n,
    const float* __restrict__ g_m1, const float* __restrict__ be_m1,
    const float* __restrict__ g_m2, const float* __restrict__ be_m2,
    const bf16_t* __restrict__ swIn, const bf16_t* __restrict__ swC2,
    const bf16_t* __restrict__ swM1, const bf16_t* __restrict__ swM2,
    float* __restrict__ out, int Nt)
{
    __shared__ alignas(16) bf16_t sB[4][2176];   // per-wave [16][136] bf16
    int tid = threadIdx.x, lane = tid & 63, wave = tid >> 6;
    int tb = (blockIdx.x*4 + wave)*16;
    int r = lane & 15, g = lane >> 4;
    int grow = tb + r;
    bool rv = grow < Nt;
    int rclamp = rv ? grow : (Nt - 1);

    // issue ALL tfeat loads up front (covered by the bin gather below)
    const float4* cf = (const float4*)(tfeat + (size_t)rclamp * 128);
    float4 p[8];
#pragma unroll
    for (int s = 0; s < 4; ++s) {
        p[2*s]   = cf[s*8 + g*2];
        p[2*s+1] = cf[s*8 + g*2 + 1];
    }

    // ---- bin gather-sum straight into this lane's A-frag cols {s*32+g*8..+8}
    float sums[32];
#pragma unroll
    for (int i = 0; i < 32; ++i) sums[i] = 0.f;
    int jb = rv ? off[grow] : 0, je = rv ? off[grow+1] : 0;
    for (int jr = jb; jr < je; ++jr) {
        const bf16_t* hp = hbuf + (size_t)jr*128 + g*8;
#pragma unroll
        for (int s = 0; s < 4; ++s) {
            bf16x8 hv = *(const bf16x8*)(hp + s*32);
#pragma unroll
            for (int q = 0; q < 8; ++q) sums[s*8+q] += (float)hv[q];
        }
    }
    // spill Hsum A-frags to per-wave LDS (frees 32 f32 regs; lane-local data)
#pragma unroll
    for (int s = 0; s < 4; ++s) {
        bf16x8 ah = { (bf16_t)sums[s*8+0], (bf16_t)sums[s*8+1],
                      (bf16_t)sums[s*8+2], (bf16_t)sums[s*8+3],
                      (bf16_t)sums[s*8+4], (bf16_t)sums[s*8+5],
                      (bf16_t)sums[s*8+6], (bf16_t)sums[s*8+7] };
        *(bf16x8*)&sB[wave][r*136 + s*32 + g*8] = ah;
    }

    // ---- gemm1: acc = tfeat@W_in + Hsum@W_ctx2  (s-outer; data in regs/LDS)
    floatx4 acc[8];
#pragma unroll
    for (int t = 0; t < 8; ++t) acc[t] = (floatx4){0.f,0.f,0.f,0.f};
#pragma unroll
    for (int s = 0; s < 4; ++s) {
        bf16x8 aH = *(const bf16x8*)&sB[wave][r*136 + s*32 + g*8];
#pragma unroll
        for (int t = 0; t < 8; ++t) {
            bf16x8 bF = *(const bf16x8*)&swC2[((t*4+s)*64 + lane)*8];
            acc[t] = __builtin_amdgcn_mfma_f32_16x16x32_bf16(aH, bF, acc[t], 0, 0, 0);
        }
        float4 v0 = p[2*s], v1 = p[2*s+1];
        bf16x8 aF = { (bf16_t)v0.x, (bf16_t)v0.y, (bf16_t)v0.z, (bf16_t)v0.w,
                      (bf16_t)v1.x, (bf16_t)v1.y, (bf16_t)v1.z, (bf16_t)v1.w };
#pragma unroll
        for (int t = 0; t < 8; ++t) {
            bf16x8 bF = *(const bf16x8*)&swIn[((t*4+s)*64 + lane)*8];
            acc[t] = __builtin_amdgcn_mfma_f32_16x16x32_bf16(aF, bF, acc[t], 0, 0, 0);
        }
    }
    gn_rows(acc, lane, g_n, be_n, true);

    // ---- restage -> gemm2 (W_m1)
#pragma unroll
    for (int t = 0; t < 8; ++t)
#pragma unroll
        for (int rr = 0; rr < 4; ++rr)
            sB[wave][(g*4 + rr)*136 + t*16 + r] = (bf16_t)acc[t][rr];
#pragma unroll
    for (int t = 0; t < 8; ++t) acc[t] = (floatx4){0.f,0.f,0.f,0.f};
#pragma unroll
    for (int s = 0; s < 4; ++s) {
        bf16x8 aF = *(const bf16x8*)&sB[wave][r*136 + s*32 + g*8];
#pragma unroll
        for (int t = 0; t < 8; ++t) {
            bf16x8 bF = *(const bf16x8*)&swM1[((t*4+s)*64 + lane)*8];
            acc[t] = __builtin_amdgcn_mfma_f32_16x16x32_bf16(aF, bF, acc[t], 0, 0, 0);
        }
    }
    gn_rows(acc, lane, g_m1, be_m1, true);

    // ---- restage -> gemm3 (W_m2)
#pragma unroll
    for (int t = 0; t < 8; ++t)
#pragma unroll
        for (int rr = 0; rr < 4; ++rr)
            sB[wave][(g*4 + rr)*136 + t*16 + r] = (bf16_t)acc[t][rr];
#pragma unroll
    for (int t = 0; t < 8; ++t) acc[t] = (floatx4){0.f,0.f,0.f,0.f};
#pragma unroll
    for (int s = 0; s < 4; ++s) {
        bf16x8 aF = *(const bf16x8*)&sB[wave][r*136 + s*32 + g*8];
#pragma unroll
        for (int t = 0; t < 8; ++t) {
            bf16x8 bF = *(const bf16x8*)&swM2[((t*4+s)*64 + lane)*8];
            acc[t] = __builtin_amdgcn_mfma_f32_16x16x32_bf16(aF, bF, acc[t], 0, 0, 0);
        }
    }
    gn_rows(acc, lane, g_m2, be_m2, false);

    // ---- epilogue: +identity, relu, direct C-layout stores (64B segments)
#pragma unroll
    for (int t = 0; t < 8; ++t) {
        int n = t*16 + r;
#pragma unroll
        for (int rr = 0; rr < 4; ++rr) {
            int row = tb + g*4 + rr;
            if (row < Nt) {
                float v = acc[t][rr] + tfeat[(size_t)row*128 + n];
                out[(size_t)row*128 + n] = fmaxf(v, 0.f);
            }
        }
    }
}

// ===========================================================================
// FALLBACK PATH (previous kernels, used only if workspace is too small for
// the binned h buffer).
// ===========================================================================
__global__ __launch_bounds__(256) void k_gemm_in(
    const float* __restrict__ tfeat, const bf16_t* __restrict__ swW,
    float* __restrict__ tf, int Nt)
{
    __shared__ alignas(16) bf16_t sA[4][2048];
    int tid = threadIdx.x, lane = tid & 63, wave = tid >> 6;

    int tb = (blockIdx.x * 4 + wave) * 16;
    int r = lane >> 2, cb = (lane & 3) * 32;
    int grow = tb + r;
    bool rv = grow < Nt;
    const float4* src = (const float4*)(tfeat + (size_t)(rv ? grow : 0) * 128 + cb);
#pragma unroll
    for (int i = 0; i < 8; ++i) {
        float4 v = rv ? src[i] : make_float4(0.f,0.f,0.f,0.f);
        int k = cb + 4*i;
        int s = k >> 5, q = (k >> 3) & 3, j = k & 7;
        bf16x4 pk = { (bf16_t)v.x, (bf16_t)v.y, (bf16_t)v.z, (bf16_t)v.w };
        *(bf16x4*)&sA[wave][(s*64 + q*16 + r)*8 + j] = pk;
    }
    __syncthreads();
    int m = lane & 15, g = lane >> 4;
    bf16x8 aF[4];
#pragma unroll
    for (int s = 0; s < 4; ++s) aF[s] = *(const bf16x8*)&sA[wave][(s*64 + lane)*8];
#pragma unroll
    for (int t = 0; t < 8; ++t) {
        floatx4 a = {0.f,0.f,0.f,0.f};
#pragma unroll
        for (int s = 0; s < 4; ++s) {
            bf16x8 bF = *(const bf16x8*)&swW[((t*4+s)*64 + lane)*8];
            a = __builtin_amdgcn_mfma_f32_16x16x32_bf16(aF[s], bF, a, 0, 0, 0);
        }
#pragma unroll
        for (int rr = 0; rr < 4; ++rr) {
            int row = tb + g*4 + rr;
            if (row < Nt) tf[(size_t)row*128 + t*16 + m] = a[rr];
        }
    }
}

__global__ __launch_bounds__(256) void k_edge_old(
    const float* __restrict__ cfeat, const float* __restrict__ cpose,
    const float* __restrict__ tpose, const int* __restrict__ hi,
    const int* __restrict__ wi, const float* __restrict__ W_rp,
    const float* __restrict__ b_rp, const float* __restrict__ g_ctx,
    const float* __restrict__ be_ctx, const bf16_t* __restrict__ swC1,
    const bf16_t* __restrict__ swC2, float* __restrict__ tf, int E)
{
    __shared__ alignas(16) bf16_t sA[4][4096];
    int tid = threadIdx.x, lane = tid & 63, wave = tid >> 6;

    int tb = (blockIdx.x * 4 + wave) * 16;
    int r = lane >> 2, cb = (lane & 3) * 32;
    int e = min(tb + r, E - 1);
    int ci = hi[e], ti = wi[e];
    const float4* src = (const float4*)(cfeat + (size_t)ci * 128 + cb);
#pragma unroll
    for (int i = 0; i < 8; ++i) {
        float4 v = src[i];
        int k = cb + 4*i;
        int s = k >> 5, q = (k >> 3) & 3, j = k & 7;
        bf16x4 pk = { (bf16_t)v.x, (bf16_t)v.y, (bf16_t)v.z, (bf16_t)v.w };
        *(bf16x4*)&sA[wave][(s*64 + q*16 + r)*8 + j] = pk;
    }
    float4 cp = ((const float4*)cpose)[ci];
    float4 tp = ((const float4*)tpose)[ti];
    float d0 = cp.x - tp.x, d1 = cp.y - tp.y, d2 = cp.z - tp.z, d3 = cp.w - tp.w;
#pragma unroll
    for (int i = 0; i < 8; ++i) {
        int cc = cb + 4*i;
        float4 w0 = *(const float4*)(W_rp + cc);
        float4 w1 = *(const float4*)(W_rp + 128 + cc);
        float4 w2 = *(const float4*)(W_rp + 256 + cc);
        float4 w3 = *(const float4*)(W_rp + 384 + cc);
        float4 bb = *(const float4*)(b_rp + cc);
        float o0 = fmaxf(d0*w0.x + d1*w1.x + d2*w2.x + d3*w3.x + bb.x, 0.f);
        float o1 = fmaxf(d0*w0.y + d1*w1.y + d2*w2.y + d3*w3.y + bb.y, 0.f);
        float o2 = fmaxf(d0*w0.z + d1*w1.z + d2*w2.z + d3*w3.z + bb.z, 0.f);
        float o3 = fmaxf(d0*w0.w + d1*w1.w + d2*w2.w + d3*w3.w + bb.w, 0.f);
        int k = 128 + cc;
        int s = k >> 5, q = (k >> 3) & 3, j = k & 7;
        bf16x4 pk = { (bf16_t)o0, (bf16_t)o1, (bf16_t)o2, (bf16_t)o3 };
        *(bf16x4*)&sA[wave][(s*64 + q*16 + r)*8 + j] = pk;
    }
    __syncthreads();

    int m = lane & 15, g = lane >> 4;
    bf16x8 aF[8];
#pragma unroll
    for (int s = 0; s < 8; ++s) aF[s] = *(const bf16x8*)&sA[wave][(s*64 + lane)*8];
    floatx4 acc[8];
#pragma unroll
    for (int t = 0; t < 8; ++t) {
        floatx4 a = {0.f,0.f,0.f,0.f};
#pragma unroll
        for (int s = 0; s < 8; ++s) {
            bf16x8 bF = *(const bf16x8*)&swC1[(size_t)((t*8+s)*64 + lane)*8];
            a = __builtin_amdgcn_mfma_f32_16x16x32_bf16(aF[s], bF, a, 0, 0, 0);
        }
        acc[t] = a;
    }
    gn_rows(acc, lane, g_ctx, be_ctx, true);
    __syncthreads();
#pragma unroll
    for (int t = 0; t < 8; ++t) {
        int n = t*16 + m;
        int s = n >> 5, q = (n >> 3) & 3, j = n & 7;
#pragma unroll
        for (int rr = 0; rr < 4; ++rr)
            sA[wave][(s*64 + q*16 + (g*4+rr))*8 + j] = (bf16_t)acc[t][rr];
    }
    __syncthreads();
    bf16x8 aF2[4];
#pragma unroll
    for (int s = 0; s < 4; ++s) aF2[s] = *(const bf16x8*)&sA[wave][(s*64 + lane)*8];
    int dstrow[4]; bool vald[4];
#pragma unroll
    for (int rr = 0; rr < 4; ++rr) {
        int ee = tb + g*4 + rr;
        vald[rr] = ee < E;
        dstrow[rr] = vald[rr] ? wi[ee] : 0;
    }
#pragma unroll
    for (int t = 0; t < 8; ++t) {
        floatx4 a = {0.f,0.f,0.f,0.f};
#pragma unroll
        for (int s = 0; s < 4; ++s) {
            bf16x8 bF = *(const bf16x8*)&swC2[((t*4+s)*64 + lane)*8];
            a = __builtin_amdgcn_mfma_f32_16x16x32_bf16(aF2[s], bF, a, 0, 0, 0);
        }
#pragma unroll
        for (int rr = 0; rr < 4; ++rr) {
            if (vald[rr])
                atomicAdd(&tf[(size_t)dstrow[rr]*128 + t*16 + m], a[rr]);
        }
    }
}

__global__ __launch_bounds__(256) void k_out_old(
    const float* __restrict__ tf, const float* __restrict__ identity,
    const float* __restrict__ g_n, const float* __restrict__ be_n,
    const float* __restrict__ g_m1, const float* __restrict__ be_m1,
    const float* __restrict__ g_m2, const float* __restrict__ be_m2,
    const bf16_t* __restrict__ swM1, const bf16_t* __restrict__ swM2,
    float* __restrict__ out, int Nt)
{
    __shared__ alignas(16) bf16_t sA[4][2048];
    int tid = threadIdx.x, lane = tid & 63, wave = tid >> 6;

    int tb = (blockIdx.x*4 + wave)*16;
    int r = lane >> 2, cb = (lane & 3)*32;
    int grow = tb + r;
    bool rv = grow < Nt;
    const float4* src = (const float4*)(tf + (size_t)(rv ? grow : 0)*128 + cb);
    float vals[32];
    float ls = 0.f, lq = 0.f;
#pragma unroll
    for (int i = 0; i < 8; ++i) {
        float4 v = rv ? src[i] : make_float4(0.f,0.f,0.f,0.f);
        vals[4*i+0]=v.x; vals[4*i+1]=v.y; vals[4*i+2]=v.z; vals[4*i+3]=v.w;
        ls += v.x+v.y+v.z+v.w;
        lq += v.x*v.x+v.y*v.y+v.z*v.z+v.w*v.w;
    }
    ls += __shfl_xor(ls,1); lq += __shfl_xor(lq,1);
    ls += __shfl_xor(ls,2); lq += __shfl_xor(lq,2);
    float mean = ls*(1.f/128.f);
    float inv = rsqrtf(lq*(1.f/128.f) - mean*mean + EPSF);
#pragma unroll
    for (int i = 0; i < 8; ++i) {
        int cc = cb + 4*i;
        float4 ga = *(const float4*)(g_n + cc);
        float4 be = *(const float4*)(be_n + cc);
        float o0 = fmaxf((vals[4*i+0]-mean)*inv*ga.x + be.x, 0.f);
        float o1 = fmaxf((vals[4*i+1]-mean)*inv*ga.y + be.y, 0.f);
        float o2 = fmaxf((vals[4*i+2]-mean)*inv*ga.z + be.z, 0.f);
        float o3 = fmaxf((vals[4*i+3]-mean)*inv*ga.w + be.w, 0.f);
        int s = cc >> 5, q = (cc >> 3) & 3, j = cc & 7;
        bf16x4 pk = { (bf16_t)o0, (bf16_t)o1, (bf16_t)o2, (bf16_t)o3 };
        *(bf16x4*)&sA[wave][(s*64 + q*16 + r)*8 + j] = pk;
    }
    __syncthreads();
    int m = lane & 15, g = lane >> 4;
    bf16x8 aF[4];
#pragma unroll
    for (int s = 0; s < 4; ++s) aF[s] = *(const bf16x8*)&sA[wave][(s*64 + lane)*8];
    floatx4 acc[8];
#pragma unroll
    for (int t = 0; t < 8; ++t) {
        floatx4 a = {0.f,0.f,0.f,0.f};
#pragma unroll
        for (int s = 0; s < 4; ++s) {
            bf16x8 bF = *(const bf16x8*)&swM1[((t*4+s)*64 + lane)*8];
            a = __builtin_amdgcn_mfma_f32_16x16x32_bf16(aF[s], bF, a, 0, 0, 0);
        }
        acc[t] = a;
    }
    gn_rows(acc, lane, g_m1, be_m1, true);
    __syncthreads();
#pragma unroll
    for (int t = 0; t < 8; ++t) {
        int n = t*16 + m;
        int s = n >> 5, q = (n >> 3) & 3, j = n & 7;
#pragma unroll
        for (int rr = 0; rr < 4; ++rr)
            sA[wave][(s*64 + q*16 + (g*4+rr))*8 + j] = (bf16_t)acc[t][rr];
    }
    __syncthreads();
#pragma unroll
    for (int s = 0; s < 4; ++s) aF[s] = *(const bf16x8*)&sA[wave][(s*64 + lane)*8];
#pragma unroll
    for (int t = 0; t < 8; ++t) {
        floatx4 a = {0.f,0.f,0.f,0.f};
#pragma unroll
        for (int s = 0; s < 4; ++s) {
            bf16x8 bF = *(const bf16x8*)&swM2[((t*4+s)*64 + lane)*8];
            a = __builtin_amdgcn_mfma_f32_16x16x32_bf16(aF[s], bF, a, 0, 0, 0);
        }
        acc[t] = a;
    }
    gn_rows(acc, lane, g_m2, be_m2, false);
#pragma unroll
    for (int t = 0; t < 8; ++t) {
        int n = t*16 + m;
#pragma unroll
        for (int rr = 0; rr < 4; ++rr) {
            int row = tb + g*4 + rr;
            if (row < Nt) {
                float v = acc[t][rr] + identity[(size_t)row*128 + n];
                out[(size_t)row*128 + n] = fmaxf(v, 0.f);
            }
        }
    }
}

// ---------------------------------------------------------------------------
extern "C" void kernel_launch(void* const* d_in, const int* in_sizes, int n_in,
                              void* d_out, int out_size, void* d_ws, size_t ws_size,
                              hipStream_t stream)
{
    const float* cfeat  = (const float*)d_in[0];
    const float* tfeat  = (const float*)d_in[1];
    const float* cpose  = (const float*)d_in[2];
    const float* tpose  = (const float*)d_in[3];
    const int*   hi     = (const int*)d_in[4];
    const int*   wi     = (const int*)d_in[5];
    const float* W_in   = (const float*)d_in[6];
    const float* W_rp   = (const float*)d_in[7];
    const float* b_rp   = (const float*)d_in[8];
    const float* W_ctx1 = (const float*)d_in[9];
    const float* g_ctx  = (const float*)d_in[10];
    const float* be_ctx = (const float*)d_in[11];
    const float* W_ctx2 = (const float*)d_in[12];
    const float* g_n    = (const float*)d_in[13];
    const float* be_n   = (const float*)d_in[14];
    const float* W_m1   = (const float*)d_in[15];
    const float* g_m1   = (const float*)d_in[16];
    const float* be_m1  = (const float*)d_in[17];
    const float* W_m2   = (const float*)d_in[18];
    const float* g_m2   = (const float*)d_in[19];
    const float* be_m2  = (const float*)d_in[20];

    int Nt = in_sizes[1] / 128;
    int E  = in_sizes[4];
    float* outp = (float*)d_out;

    // new-path workspace layout
    char* base = (char*)d_ws;
    size_t o = 98304 * sizeof(bf16_t);                 // sw @ 0
    o = (o + 255) & ~(size_t)255;
    size_t o_cnt = o; o += (size_t)Nt * 4;
    o = (o + 255) & ~(size_t)255;
    size_t o_off = o; o += ((size_t)Nt + 1) * 4;
    o = (o + 255) & ~(size_t)255;
    size_t o_cur = o; o += (size_t)Nt * 4;
    o = (o + 255) & ~(size_t)255;
    size_t o_h = o; o += (size_t)E * 128 * sizeof(bf16_t);

    if (ws_size >= o) {
        bf16_t* sw   = (bf16_t*)base;
        int*    cnt  = (int*)(base + o_cnt);
        int*    off  = (int*)(base + o_off);
        int*    cur  = (int*)(base + o_cur);
        bf16_t* hbuf = (bf16_t*)(base + o_h);
        bf16_t* swIn = sw;
        bf16_t* swC1 = sw + 16384;
        bf16_t* swC2 = sw + 49152;
        bf16_t* swM1 = sw + 65536;
        bf16_t* swM2 = sw + 81920;

        hipMemsetAsync(cnt, 0, (size_t)Nt * 4, stream);
        hipMemsetAsync(cur, 0, (size_t)Nt * 4, stream);
        k_prep<<<384, 256, 0, stream>>>(W_in, W_ctx1, W_ctx2, W_m1, W_m2, sw);
        k_count<<<(E + 255) / 256, 256, 0, stream>>>(wi, cnt, E);
        k_scan<<<1, 1024, 0, stream>>>(cnt, off, Nt);
        k_edge6<<<(E + 127) / 128, 256, 0, stream>>>(cfeat, cpose, tpose, hi, wi,
                                                     W_rp, b_rp, g_ctx, be_ctx,
                                                     swC1, off, cur, hbuf, E);
        k_out3<<<(Nt + 63) / 64, 256, 0, stream>>>(tfeat, hbuf, off,
                                                   g_n, be_n, g_m1, be_m1,
                                                   g_m2, be_m2,
                                                   swIn, swC2, swM1, swM2,
                                                   outp, Nt);
    } else {
        // fallback: previous atomic-scatter path
        float*  tf = (float*)d_ws;                                   // [Nt,128] f32
        bf16_t* sw = (bf16_t*)((char*)d_ws + (size_t)Nt * 128 * sizeof(float));
        bf16_t* swIn = sw;
        bf16_t* swC1 = sw + 16384;
        bf16_t* swC2 = sw + 49152;
        bf16_t* swM1 = sw + 65536;
        bf16_t* swM2 = sw + 81920;

        k_prep<<<384, 256, 0, stream>>>(W_in, W_ctx1, W_ctx2, W_m1, W_m2, sw);
        k_gemm_in<<<(Nt + 63) / 64, 256, 0, stream>>>(tfeat, swIn, tf, Nt);
        k_edge_old<<<(E + 63) / 64, 256, 0, stream>>>(cfeat, cpose, tpose, hi, wi,
                                                      W_rp, b_rp, g_ctx, be_ctx,
                                                      swC1, swC2, tf, E);
        k_out_old<<<(Nt + 63) / 64, 256, 0, stream>>>(tf, tfeat, g_n, be_n,
                                                      g_m1, be_m1, g_m2, be_m2,
                                                      swM1, swM2, outp, Nt);
    }
}